// Round 13
// baseline (2644.544 us; speedup 1.0000x reference)
//
#include <hip/hip_runtime.h>
#include <hip/hip_bf16.h>

#define EPSV 1e-5f
#define NSTRIPE 16

typedef unsigned int uint;
typedef unsigned short ushort;
typedef __attribute__((ext_vector_type(8))) __bf16 bf16x8;
typedef __attribute__((ext_vector_type(4))) float f32x4;

static __device__ __forceinline__ float bf2f(ushort u) {
    return __uint_as_float(((uint)u) << 16);
}
static __device__ __forceinline__ ushort f2bf(float f) {
    __hip_bfloat16 h = __float2bfloat16(f);
    return __builtin_bit_cast(ushort, h);
}

// ---------------- fp8 e4m3 codec (low-mem skip tier) ----------------

static __device__ __forceinline__ float e4m3_dec(unsigned char b) {
    int s = b >> 7, E = (b >> 3) & 15, m = b & 7;
    float v = (E == 0) ? (float)m * 0.001953125f
                       : (float)(8 + m) * 0.125f * exp2f((float)(E - 7));
    return s ? -v : v;
}
static __device__ __forceinline__ unsigned char e4m3_enc(float f) {
    unsigned su = (__float_as_uint(f) >> 24) & 0x80u;
    float a = fabsf(f);
    if (!(a < 448.f)) return (unsigned char)(su | 0x7E);
    if (a < 0.015625f) {
        int m = (int)rintf(a * 512.f);
        return (unsigned char)(su | (m >= 8 ? 0x08 : m));
    }
    int e;
    frexpf(a, &e);
    int E = e - 1 + 7;
    float mant = a * exp2f((float)(1 - e)) - 1.0f;
    int mi = (int)rintf(mant * 8.f);
    if (mi >= 8) { mi = 0; E++; }
    if (E >= 16) return (unsigned char)(su | 0x7E);
    if (E == 15 && mi == 7) mi = 6;
    return (unsigned char)(su | (E << 3) | mi);
}

// ---------------- storage traits ----------------

template <typename T> struct IOV;
template <> struct IOV<float> {
    static __device__ __forceinline__ float2 ld2(const float* p) { return *(const float2*)p; }
    static __device__ __forceinline__ void st2(float* p, float a, float b) {
        *(float2*)p = make_float2(a, b);
    }
    static __device__ __forceinline__ void st1(float* p, float v) { *p = v; }
    static __device__ __forceinline__ void ld8(const float* p, float* v) {
        float4 a = ((const float4*)p)[0], b = ((const float4*)p)[1];
        v[0] = a.x; v[1] = a.y; v[2] = a.z; v[3] = a.w;
        v[4] = b.x; v[5] = b.y; v[6] = b.z; v[7] = b.w;
    }
    static __device__ __forceinline__ void st8(float* p, const float* v) {
        ((float4*)p)[0] = make_float4(v[0], v[1], v[2], v[3]);
        ((float4*)p)[1] = make_float4(v[4], v[5], v[6], v[7]);
    }
};
template <> struct IOV<ushort> {  // bf16 bits
    static __device__ __forceinline__ float2 ld2(const ushort* p) {
        uint u = *(const uint*)p;
        return make_float2(bf2f((ushort)u), bf2f((ushort)(u >> 16)));
    }
    static __device__ __forceinline__ void st2(ushort* p, float a, float b) {
        *(uint*)p = (uint)f2bf(a) | ((uint)f2bf(b) << 16);
    }
    static __device__ __forceinline__ void st1(ushort* p, float v) { *p = f2bf(v); }
    static __device__ __forceinline__ void ld8(const ushort* p, float* v) {
        uint4 u = *(const uint4*)p;
        v[0] = bf2f((ushort)u.x); v[1] = bf2f((ushort)(u.x >> 16));
        v[2] = bf2f((ushort)u.y); v[3] = bf2f((ushort)(u.y >> 16));
        v[4] = bf2f((ushort)u.z); v[5] = bf2f((ushort)(u.z >> 16));
        v[6] = bf2f((ushort)u.w); v[7] = bf2f((ushort)(u.w >> 16));
    }
    static __device__ __forceinline__ void st8(ushort* p, const float* v) {
        uint4 u;
        u.x = (uint)f2bf(v[0]) | ((uint)f2bf(v[1]) << 16);
        u.y = (uint)f2bf(v[2]) | ((uint)f2bf(v[3]) << 16);
        u.z = (uint)f2bf(v[4]) | ((uint)f2bf(v[5]) << 16);
        u.w = (uint)f2bf(v[6]) | ((uint)f2bf(v[7]) << 16);
        *(uint4*)p = u;
    }
};
template <> struct IOV<unsigned char> {  // fp8 e4m3
    static __device__ __forceinline__ float2 ld2(const unsigned char* p) {
        ushort u = *(const ushort*)p;
        return make_float2(e4m3_dec((unsigned char)u), e4m3_dec((unsigned char)(u >> 8)));
    }
    static __device__ __forceinline__ void st2(unsigned char* p, float a, float b) {
        *(ushort*)p = (ushort)e4m3_enc(a) | ((ushort)e4m3_enc(b) << 8);
    }
    static __device__ __forceinline__ void st1(unsigned char* p, float v) { *p = e4m3_enc(v); }
    static __device__ __forceinline__ void ld8(const unsigned char* p, float* v) {
        uint2 u = *(const uint2*)p;
#pragma unroll
        for (int j = 0; j < 4; j++) v[j] = e4m3_dec((unsigned char)(u.x >> (8 * j)));
#pragma unroll
        for (int j = 0; j < 4; j++) v[4 + j] = e4m3_dec((unsigned char)(u.y >> (8 * j)));
    }
    static __device__ __forceinline__ void st8(unsigned char* p, const float* v) {
        uint2 u = {0, 0};
#pragma unroll
        for (int j = 0; j < 4; j++) u.x |= (uint)e4m3_enc(v[j]) << (8 * j);
#pragma unroll
        for (int j = 0; j < 4; j++) u.y |= (uint)e4m3_enc(v[4 + j]) << (8 * j);
        *(uint2*)p = u;
    }
};

// ---------------- graph setup ----------------

__global__ void k_count(const int* __restrict__ dst, int* __restrict__ cnt, int E) {
    int e = blockIdx.x * blockDim.x + threadIdx.x;
    if (e < E) atomicAdd(&cnt[dst[e]], 1);
}

// sums PADDED counts (rows padded to multiple of 16)
__global__ void k_scan1(const int* __restrict__ cnt, int* __restrict__ bsum, int N) {
    __shared__ int s[256];
    int i = blockIdx.x * 256 + threadIdx.x;
    s[threadIdx.x] = (i < N) ? ((cnt[i] + 15) & ~15) : 0;
    __syncthreads();
    for (int o = 128; o > 0; o >>= 1) {
        if (threadIdx.x < o) s[threadIdx.x] += s[threadIdx.x + o];
        __syncthreads();
    }
    if (threadIdx.x == 0) bsum[blockIdx.x] = s[0];
}

__global__ void k_scan2(int* __restrict__ bsum, int B) {
    __shared__ int s[1024];
    int t = threadIdx.x;
    int orig = (t < B) ? bsum[t] : 0;
    s[t] = orig;
    __syncthreads();
    for (int o = 1; o < 1024; o <<= 1) {
        int v = (t >= o) ? s[t - o] : 0;
        __syncthreads();
        s[t] += v;
        __syncthreads();
    }
    if (t < B) bsum[t] = s[t] - orig;
}

__global__ void k_scan3(const int* __restrict__ cnt, const int* __restrict__ bsum,
                        int* __restrict__ roff, int* __restrict__ cursor,
                        float* __restrict__ dinv, int N) {
    __shared__ int s[256];
    int i = blockIdx.x * 256 + threadIdx.x;
    int v = (i < N) ? cnt[i] : 0;
    int pv = (v + 15) & ~15;
    s[threadIdx.x] = pv;
    __syncthreads();
    for (int o = 1; o < 256; o <<= 1) {
        int u = (threadIdx.x >= o) ? s[threadIdx.x - o] : 0;
        __syncthreads();
        s[threadIdx.x] += u;
        __syncthreads();
    }
    if (i < N) {
        int off = bsum[blockIdx.x] + s[threadIdx.x] - pv;
        roff[i] = off;
        cursor[i] = off;
        dinv[i] = rsqrtf((float)(v + 1));
        if (i == N - 1) roff[N] = off + pv;
    }
}

__global__ void k_scatter(const int* __restrict__ src, const int* __restrict__ dst,
                          const float* __restrict__ dinv, int* __restrict__ cursor,
                          int2* __restrict__ ev, int E) {
    int e = blockIdx.x * blockDim.x + threadIdx.x;
    if (e < E) {
        int s = src[e], d = dst[e];
        int p = atomicAdd(&cursor[d], 1);
        int2 pk;
        pk.x = s;
        pk.y = __float_as_int(dinv[s] * dinv[d]);
        ev[p] = pk;
    }
}

// fill pad slots with zero-weight self edges
__global__ void k_pad(const int* __restrict__ cursor, const int* __restrict__ roff,
                      int2* __restrict__ ev, int N) {
    int i = blockIdx.x * blockDim.x + threadIdx.x;
    if (i >= N) return;
    int p = cursor[i], e = roff[i + 1];
    int2 pk;
    pk.x = i;
    pk.y = 0;
    for (; p < e; p++) ev[p] = pk;
}

// precompute fragment-ordered bf16 hi/lo for all 17 dense weight matrices
__global__ void k_prepw(const float* __restrict__ Ws1, const float* __restrict__ Ws2,
                        ushort* __restrict__ whi, ushort* __restrict__ wlo) {
    int idx = blockIdx.x * blockDim.x + threadIdx.x;
    if (idx >= 17 * 16384) return;
    int L = idx >> 14, r = idx & 16383;
    int f = r >> 9, e = r & 511, lane = e >> 3, j = e & 7;
    int n = (f >> 2) * 16 + (lane & 15);
    int k = (f & 3) * 32 + (lane >> 4) * 8 + j;
    const float* W = (L < 9) ? (Ws1 + (size_t)L * 16384) : (Ws2 + (size_t)(L - 9) * 16384);
    float w = W[(size_t)k * 128 + n];
    ushort hi = f2bf(w);
    whi[idx] = hi;
    wlo[idx] = f2bf(w - bf2f(hi));
}

// ---------------- sparse ops ----------------

__global__ void k_spmm3(const float* __restrict__ X, const int2* __restrict__ ev,
                        const int* __restrict__ roff, const float* __restrict__ dinv,
                        float* __restrict__ XA, int N) {
    int i = blockIdx.x * blockDim.x + threadIdx.x;
    if (i >= N) return;
    float di = dinv[i];
    float w0 = di * di;
    float a0 = X[(size_t)i * 3 + 0] * w0;
    float a1 = X[(size_t)i * 3 + 1] * w0;
    float a2 = X[(size_t)i * 3 + 2] * w0;
    int je = roff[i + 1];
    for (int j = roff[i]; j < je; j++) {
        int2 e = ev[j];
        float w = __int_as_float(e.y);
        a0 += X[(size_t)e.x * 3 + 0] * w;
        a1 += X[(size_t)e.x * 3 + 1] * w;
        a2 += X[(size_t)e.x * 3 + 2] * w;
    }
    XA[(size_t)i * 3 + 0] = a0;
    XA[(size_t)i * 3 + 1] = a1;
    XA[(size_t)i * 3 + 2] = a2;
}

// Z(pre-BN) = A @ H (H bf16) + fused striped stats.
// CHANNEL-HALF SPLIT: half = blockIdx&1 -> with round-robin block->XCD mapping,
// even XCDs gather only cols 0-63 of H, odd only 64-127 -> per-XCD working set
// halves (25.6 -> 12.8 MB) -> HBM fetch from cross-XCD duplication halves.
// Each wave: 4 rows serial, lane = channel within half, 16-deep gather pipeline.
template <typename ZT>
__global__ __launch_bounds__(256) void k_spmm_stats(
    const ushort* __restrict__ H, const int2* __restrict__ ev,
    const int* __restrict__ roff, const float* __restrict__ dinv,
    ZT* __restrict__ Y, float* __restrict__ st, int N) {
    int lane = threadIdx.x & 63, wv = threadIdx.x >> 6;
    int half = blockIdx.x & 1;
    int rblk = blockIdx.x >> 1;
    int c = half * 64 + lane;
    float s = 0.f, q = 0.f;

#pragma unroll
    for (int r = 0; r < 4; r++) {
        int i = rblk * 16 + wv * 4 + r;
        if (i >= N) break;
        float di = dinv[i];
        float a = bf2f(H[(size_t)i * 128 + c]) * di * di;
        int j = roff[i], je = roff[i + 1];
        for (; j < je; j += 16) {
            int2 e[16];
            ushort hv[16];
#pragma unroll
            for (int t = 0; t < 16; t++) e[t] = ev[j + t];
#pragma unroll
            for (int t = 0; t < 16; t++) hv[t] = H[(size_t)e[t].x * 128 + c];
#pragma unroll
            for (int t = 0; t < 16; t++) a += bf2f(hv[t]) * __int_as_float(e[t].y);
        }
        IOV<ZT>::st1(&Y[(size_t)i * 128 + c], a);
        s += a;
        q += a * a;
    }

    __shared__ float ls[4][64][2];
    ls[wv][lane][0] = s;
    ls[wv][lane][1] = q;
    __syncthreads();
    if (wv == 0) {
        s = ls[0][lane][0] + ls[1][lane][0] + ls[2][lane][0] + ls[3][lane][0];
        q = ls[0][lane][1] + ls[1][lane][1] + ls[2][lane][1] + ls[3][lane][1];
        float* stp = st + (size_t)(rblk & (NSTRIPE - 1)) * 256;
        atomicAdd(&stp[c], s);
        atomicAdd(&stp[128 + c], q);
    }
}

__global__ void k_spmm1(const float* __restrict__ T, const int2* __restrict__ ev,
                        const int* __restrict__ roff, const float* __restrict__ dinv,
                        float* __restrict__ out, int N) {
    int i = blockIdx.x * blockDim.x + threadIdx.x;
    if (i >= N) return;
    float di = dinv[i];
    float a = T[i] * di * di;
    int je = roff[i + 1];
    for (int j = roff[i]; j < je; j++) {
        int2 e = ev[j];
        a += T[e.x] * __int_as_float(e.y);
    }
    out[i] = 1.0f / (1.0f + expf(-a));
}

// finalize striped stats -> affine (for k_dot only)
__global__ void k_bnfin(const float* __restrict__ st, const float* __restrict__ g,
                        const float* __restrict__ b, float* __restrict__ aff, float invN) {
    int c = threadIdx.x;  // 128
    float S = 0.f, Q = 0.f;
    for (int s = 0; s < NSTRIPE; s++) {
        S += st[(size_t)s * 256 + c];
        Q += st[(size_t)s * 256 + 128 + c];
    }
    float m = S * invN;
    float var = Q * invN - m * m;
    float sc = g[c] * rsqrtf(var + EPSV);
    aff[c] = sc;
    aff[128 + c] = b[c] - m * sc;
}

// ---------------- dense ops ----------------

// z(stage0, pre-BN) = (A@x)@W0 with fused striped stats; 16 rows/block (4/wave)
template <typename ZT>
__global__ __launch_bounds__(256) void k_gemm3_stats(
    const float* __restrict__ XA, const float* __restrict__ W0,
    ZT* __restrict__ Y, float* __restrict__ st, int N) {
    int lane = threadIdx.x & 63, wv = threadIdx.x >> 6;
    int c0 = lane * 2;
    float w00 = W0[c0], w10 = W0[128 + c0], w20 = W0[256 + c0];
    float w01 = W0[c0 + 1], w11 = W0[128 + c0 + 1], w21 = W0[256 + c0 + 1];
    float s0 = 0.f, s1 = 0.f, q0 = 0.f, q1 = 0.f;
#pragma unroll
    for (int r = 0; r < 4; r++) {
        int i = blockIdx.x * 16 + wv * 4 + r;
        if (i >= N) break;
        float x0 = XA[(size_t)i * 3], x1 = XA[(size_t)i * 3 + 1], x2 = XA[(size_t)i * 3 + 2];
        float y0 = x0 * w00 + x1 * w10 + x2 * w20;
        float y1 = x0 * w01 + x1 * w11 + x2 * w21;
        IOV<ZT>::st2(&Y[(size_t)i * 128 + c0], y0, y1);
        s0 += y0; q0 += y0 * y0;
        s1 += y1; q1 += y1 * y1;
    }
    __shared__ float ls[4][64][4];
    ls[wv][lane][0] = s0; ls[wv][lane][1] = s1;
    ls[wv][lane][2] = q0; ls[wv][lane][3] = q1;
    __syncthreads();
    if (wv == 0) {
        s0 = ls[0][lane][0] + ls[1][lane][0] + ls[2][lane][0] + ls[3][lane][0];
        s1 = ls[0][lane][1] + ls[1][lane][1] + ls[2][lane][1] + ls[3][lane][1];
        q0 = ls[0][lane][2] + ls[1][lane][2] + ls[2][lane][2] + ls[3][lane][2];
        q1 = ls[0][lane][3] + ls[1][lane][3] + ls[2][lane][3] + ls[3][lane][3];
        float* stp = st + (size_t)(blockIdx.x & (NSTRIPE - 1)) * 256;
        atomicAdd(&stp[2 * lane], s0);
        atomicAdd(&stp[2 * lane + 1], s1);
        atomicAdd(&stp[128 + 2 * lane], q0);
        atomicAdd(&stp[129 + 2 * lane], q1);
    }
}

// H(bf16) = [ReLU(BN(Z)) + skip_in] @ W  (MFMA; fragment-order W hi/lo staging)
template <typename ZT, typename SKT>
__global__ __launch_bounds__(256) void k_gemm_mfma(
    const ZT* __restrict__ Z, const SKT* __restrict__ skip_in, SKT* __restrict__ skip_out,
    const float* __restrict__ st, const float* __restrict__ gz, const float* __restrict__ bz,
    const ushort* __restrict__ whi, const ushort* __restrict__ wlo,
    ushort* __restrict__ H, float invN, int N) {
    __shared__ ushort sW[16384];  // 32 frags x 512 ushorts
    __shared__ float sA[256];
    int tid = threadIdx.x;
    int wave = tid >> 6, lane = tid & 63;
    int l15 = lane & 15, quad = lane >> 4;

    // phase A: striped-stats partial reduce (16 stripes)
    {
        float acc = 0.f;
#pragma unroll
        for (int s = 0; s < NSTRIPE; s++) acc += st[(size_t)s * 256 + tid];
        sA[tid] = acc;
    }
    // phase B: stage W hi (coalesced, fragment-ordered)
    {
        const uint4* src = (const uint4*)whi;
#pragma unroll
        for (int t = 0; t < 8; t++) ((uint4*)sW)[tid + 256 * t] = src[tid + 256 * t];
    }
    __syncthreads();
    // phase C: finalize BN affine
    if (tid < 128) {
        float S = sA[tid], Q = sA[128 + tid];
        float m = S * invN;
        float var = Q * invN - m * m;
        float sc = gz[tid] * rsqrtf(var + EPSV);
        sA[tid] = sc;
        sA[128 + tid] = bz[tid] - m * sc;
    }
    __syncthreads();

    int row = blockIdx.x * 64 + wave * 16 + l15;
    size_t rowc = (size_t)(row < N ? row : N - 1);

    bf16x8 ahi[4];
#pragma unroll
    for (int kc = 0; kc < 4; kc++) {
        int c0 = kc * 32 + quad * 8;
        float v[8];
        IOV<ZT>::ld8(&Z[rowc * 128 + c0], v);
        float av[8];
#pragma unroll
        for (int jj = 0; jj < 8; jj++) {
            float t = v[jj] * sA[c0 + jj] + sA[128 + c0 + jj];
            av[jj] = fmaxf(t, 0.f);
        }
        if (skip_out && row < N) IOV<SKT>::st8(&skip_out[rowc * 128 + c0], av);
        if (skip_in) {
            float w2[8];
            IOV<SKT>::ld8(&skip_in[rowc * 128 + c0], w2);
#pragma unroll
            for (int jj = 0; jj < 8; jj++) av[jj] += w2[jj];
        }
        bf16x8 fh;
#pragma unroll
        for (int jj = 0; jj < 8; jj++) fh[jj] = (__bf16)av[jj];
        ahi[kc] = fh;
    }

    f32x4 acc[8];
#pragma unroll
    for (int ct = 0; ct < 8; ct++) {
        f32x4 z0 = {0.f, 0.f, 0.f, 0.f};
        acc[ct] = z0;
    }

    // pass 1: Ahi * Whi
#pragma unroll
    for (int ct = 0; ct < 8; ct++) {
#pragma unroll
        for (int kc = 0; kc < 4; kc++) {
            bf16x8 b = *(const bf16x8*)&sW[(ct * 4 + kc) * 512 + lane * 8];
            acc[ct] = __builtin_amdgcn_mfma_f32_16x16x32_bf16(ahi[kc], b, acc[ct], 0, 0, 0);
        }
    }
    __syncthreads();
    // stage W lo (coalesced)
    {
        const uint4* src = (const uint4*)wlo;
#pragma unroll
        for (int t = 0; t < 8; t++) ((uint4*)sW)[tid + 256 * t] = src[tid + 256 * t];
    }
    __syncthreads();
    // pass 2: Ahi * Wlo
#pragma unroll
    for (int ct = 0; ct < 8; ct++) {
#pragma unroll
        for (int kc = 0; kc < 4; kc++) {
            bf16x8 b = *(const bf16x8*)&sW[(ct * 4 + kc) * 512 + lane * 8];
            acc[ct] = __builtin_amdgcn_mfma_f32_16x16x32_bf16(ahi[kc], b, acc[ct], 0, 0, 0);
        }
    }
    __syncthreads();
    // epilogue: C layout col=l15, row=quad*4+reg -> LDS -> coalesced bf16 store
    ushort* sC = sW;
#pragma unroll
    for (int ct = 0; ct < 8; ct++)
#pragma unroll
        for (int reg = 0; reg < 4; reg++) {
            int r = wave * 16 + quad * 4 + reg;
            sC[r * 136 + ct * 16 + l15] = f2bf(acc[ct][reg]);
        }
    __syncthreads();
    for (int t = tid; t < 1024; t += 256) {
        int r = t >> 4, c4 = t & 15;
        int grow = blockIdx.x * 64 + r;
        if (grow < N)
            ((uint4*)(H + (size_t)grow * 128))[c4] = *(const uint4*)&sC[r * 136 + c4 * 8];
    }
}

// t = [ReLU(BN(Z)) + skip0(post-act)] @ Wout  (wave per row; affine precomputed)
template <typename ZT, typename SKT>
__global__ __launch_bounds__(256) void k_dot(
    const ZT* __restrict__ Z, const SKT* __restrict__ S0,
    const float* __restrict__ aff, const float* __restrict__ Wout,
    float* __restrict__ T, int N) {
    int i = blockIdx.x * 4 + (threadIdx.x >> 6);
    if (i >= N) return;
    int lane = threadIdx.x & 63;
    int c0 = 2 * lane, c1 = c0 + 1;
    float2 z = IOV<ZT>::ld2(&Z[(size_t)i * 128 + c0]);
    float2 s = IOV<SKT>::ld2(&S0[(size_t)i * 128 + c0]);
    float p0 = fmaxf(z.x * aff[c0] + aff[128 + c0], 0.f) + s.x;
    float p1 = fmaxf(z.y * aff[c1] + aff[128 + c1], 0.f) + s.y;
    float a = p0 * Wout[c0] + p1 * Wout[c1];
    for (int o = 32; o > 0; o >>= 1) a += __shfl_down(a, o);
    if (lane == 0) T[i] = a;
}

// ---------------- templated pipeline ----------------

template <typename ZT, typename SKT>
static void run_all(const float* x, const int* src, const int* dst, const float* W0,
                    const float* Ws1, const float* g1, const float* b1,
                    const float* Ws2, const float* g2, const float* b2,
                    const float* Wout, float* out, char* ws, int N, int E,
                    hipStream_t stream) {
    char* p = ws;
    auto alloc = [&](size_t bytes) -> void* {
        void* r = (void*)p;
        p += (bytes + 255) & ~(size_t)255;
        return r;
    };
    size_t Epad = (size_t)E + 15 * (size_t)N + 16;
    int*   roff   = (int*)alloc((size_t)(N + 1) * 4);
    float* dinv   = (float*)alloc((size_t)N * 4);
    int2*  ev     = (int2*)alloc(Epad * 8);
    int*   bsum   = (int*)alloc(4096);
    float* st_all = (float*)alloc((size_t)18 * NSTRIPE * 256 * 4);
    float* aff    = (float*)alloc(1024);
    ushort* whi   = (ushort*)alloc((size_t)17 * 16384 * 2);
    ushort* wlo   = (ushort*)alloc((size_t)17 * 16384 * 2);
    size_t nz = (size_t)N * 128;
    ushort* hb = (ushort*)alloc(nz * 2);
    ZT* zb = (ZT*)alloc(nz * sizeof(ZT));
    SKT* skips = (SKT*)alloc((size_t)9 * nz * sizeof(SKT));
    auto skip = [&](int s) { return skips + (size_t)s * nz; };
    auto stg  = [&](int s) { return st_all + (size_t)s * NSTRIPE * 256; };

    // lifetime-disjoint aliases
    int* cnt    = (int*)skip(8);
    int* cursor = (int*)((char*)skip(8) + (((size_t)N * 4 + 255) & ~(size_t)255));
    float* xa   = (float*)hb;
    float* tbuf = (float*)hb;

    float invN = 1.0f / (float)N;
    auto gb = [&](int stage, const float** g, const float** b) {
        if (stage <= 9) { *g = g1 + (size_t)stage * 128; *b = b1 + (size_t)stage * 128; }
        else { *g = g2 + (size_t)(stage - 10) * 128; *b = b2 + (size_t)(stage - 10) * 128; }
    };

    // --- setup: CSR (padded to %16) + weight prep ---
    hipMemsetAsync(st_all, 0, (size_t)18 * NSTRIPE * 256 * 4, stream);
    hipMemsetAsync(cnt, 0, (size_t)N * 4, stream);
    k_count<<<(E + 255) / 256, 256, 0, stream>>>(dst, cnt, E);
    int B = (N + 255) / 256;
    k_scan1<<<B, 256, 0, stream>>>(cnt, bsum, N);
    k_scan2<<<1, 1024, 0, stream>>>(bsum, B);
    k_scan3<<<B, 256, 0, stream>>>(cnt, bsum, roff, cursor, dinv, N);
    k_scatter<<<(E + 255) / 256, 256, 0, stream>>>(src, dst, dinv, cursor, ev, E);
    k_pad<<<(N + 255) / 256, 256, 0, stream>>>(cursor, roff, ev, N);
    k_prepw<<<(17 * 16384 + 255) / 256, 256, 0, stream>>>(Ws1, Ws2, whi, wlo);

    int gg = (N + 63) / 64;
    int gs4 = (N + 3) / 4;
    int gs16 = (N + 15) / 16;
    int gh = 2 * gs16;   // channel-half split grid

    // --- layer 0: z = (A@x)@W0 (pre-BN) + fused stats ---
    k_spmm3<<<(N + 255) / 256, 256, 0, stream>>>(x, ev, roff, dinv, xa, N);
    k_gemm3_stats<ZT><<<gs16, 256, 0, stream>>>(xa, W0, zb, stg(0), N);

    // --- down layers 1..9 ---
    for (int l = 1; l <= 9; l++) {
        const float *gzp, *bzp;
        gb(l - 1, &gzp, &bzp);
        k_gemm_mfma<ZT, SKT><<<gg, 256, 0, stream>>>(
            zb, (const SKT*)nullptr, skip(l - 1), stg(l - 1), gzp, bzp,
            whi + (size_t)(l - 1) * 16384, wlo + (size_t)(l - 1) * 16384, hb, invN, N);
        k_spmm_stats<ZT><<<gh, 256, 0, stream>>>(hb, ev, roff, dinv, zb, stg(l), N);
    }

    // --- up layers 0..7 ---
    for (int i = 0; i < 8; i++) {
        int zs = 9 + i;
        const float *gzp, *bzp;
        gb(zs, &gzp, &bzp);
        k_gemm_mfma<ZT, SKT><<<gg, 256, 0, stream>>>(
            zb, skip(8 - i), (SKT*)nullptr, stg(zs), gzp, bzp,
            whi + (size_t)(9 + i) * 16384, wlo + (size_t)(9 + i) * 16384, hb, invN, N);
        k_spmm_stats<ZT><<<gh, 256, 0, stream>>>(hb, ev, roff, dinv, zb, stg(10 + i), N);
    }

    // --- output: sigmoid(A @ ([act17(z) + skip0] @ Wout)) ---
    const float *gzp, *bzp;
    gb(17, &gzp, &bzp);
    k_bnfin<<<1, 128, 0, stream>>>(stg(17), gzp, bzp, aff, invN);
    k_dot<ZT, SKT><<<gs4, 256, 0, stream>>>(zb, skip(0), aff, Wout, tbuf, N);
    k_spmm1<<<(N + 255) / 256, 256, 0, stream>>>(tbuf, ev, roff, dinv, out, N);
}

// ---------------- launch ----------------

extern "C" void kernel_launch(void* const* d_in, const int* in_sizes, int n_in,
                              void* d_out, int out_size, void* d_ws, size_t ws_size,
                              hipStream_t stream) {
    const float* x    = (const float*)d_in[0];
    const int*   ei   = (const int*)d_in[1];
    const float* W0   = (const float*)d_in[2];
    const float* Ws1  = (const float*)d_in[3];
    const float* g1   = (const float*)d_in[4];
    const float* b1   = (const float*)d_in[5];
    const float* Ws2  = (const float*)d_in[6];
    const float* g2   = (const float*)d_in[7];
    const float* b2   = (const float*)d_in[8];
    const float* Wout = (const float*)d_in[9];
    float* out = (float*)d_out;

    int N = in_sizes[0] / 3;
    int E = in_sizes[1] / 2;
    const int* src = ei;
    const int* dst = ei + E;

    size_t nz = (size_t)N * 128;
    size_t Epad = (size_t)E + 15 * (size_t)N + 16;
    auto need = [&](size_t zbytes, size_t skbytes) -> size_t {
        size_t t = 0;
        auto add = [&](size_t b) { t += (b + 255) & ~(size_t)255; };
        add((size_t)(N + 1) * 4);
        add((size_t)N * 4);
        add(Epad * 8);
        add(4096);
        add((size_t)18 * NSTRIPE * 256 * 4);
        add(1024);
        add((size_t)17 * 16384 * 2);
        add((size_t)17 * 16384 * 2);
        add(nz * 2);
        add(nz * zbytes);
        add((size_t)9 * nz * skbytes);
        return t;
    };

    char* ws = (char*)d_ws;
    if (need(4, 2) <= ws_size)          // fp32 z, bf16 skips (~341 MB)
        run_all<float, ushort>(x, src, dst, W0, Ws1, g1, b1, Ws2, g2, b2, Wout, out, ws, N, E, stream);
    else if (need(4, 1) <= ws_size)     // fp32 z, fp8 skips (~225 MB)
        run_all<float, unsigned char>(x, src, dst, W0, Ws1, g1, b1, Ws2, g2, b2, Wout, out, ws, N, E, stream);
    else                                // bf16 z, fp8 skips (~199 MB)
        run_all<ushort, unsigned char>(x, src, dst, W0, Ws1, g1, b1, Ws2, g2, b2, Wout, out, ws, N, E, stream);
}

// Round 14
// 2126.999 us; speedup vs baseline: 1.2433x; 1.2433x over previous
//
#include <hip/hip_runtime.h>
#include <hip/hip_bf16.h>

#define EPSV 1e-5f
#define NSTRIPE 16

typedef unsigned int uint;
typedef unsigned short ushort;
typedef __attribute__((ext_vector_type(8))) __bf16 bf16x8;
typedef __attribute__((ext_vector_type(4))) float f32x4;

static __device__ __forceinline__ float bf2f(ushort u) {
    return __uint_as_float(((uint)u) << 16);
}
static __device__ __forceinline__ ushort f2bf(float f) {
    __hip_bfloat16 h = __float2bfloat16(f);
    return __builtin_bit_cast(ushort, h);
}

// ---------------- fp8 e4m3 codec (low-mem skip tier) ----------------

static __device__ __forceinline__ float e4m3_dec(unsigned char b) {
    int s = b >> 7, E = (b >> 3) & 15, m = b & 7;
    float v = (E == 0) ? (float)m * 0.001953125f
                       : (float)(8 + m) * 0.125f * exp2f((float)(E - 7));
    return s ? -v : v;
}
static __device__ __forceinline__ unsigned char e4m3_enc(float f) {
    unsigned su = (__float_as_uint(f) >> 24) & 0x80u;
    float a = fabsf(f);
    if (!(a < 448.f)) return (unsigned char)(su | 0x7E);
    if (a < 0.015625f) {
        int m = (int)rintf(a * 512.f);
        return (unsigned char)(su | (m >= 8 ? 0x08 : m));
    }
    int e;
    frexpf(a, &e);
    int E = e - 1 + 7;
    float mant = a * exp2f((float)(1 - e)) - 1.0f;
    int mi = (int)rintf(mant * 8.f);
    if (mi >= 8) { mi = 0; E++; }
    if (E >= 16) return (unsigned char)(su | 0x7E);
    if (E == 15 && mi == 7) mi = 6;
    return (unsigned char)(su | (E << 3) | mi);
}

// ---------------- storage traits ----------------

template <typename T> struct IOV;
template <> struct IOV<float> {
    static __device__ __forceinline__ float2 ld2(const float* p) { return *(const float2*)p; }
    static __device__ __forceinline__ void st2(float* p, float a, float b) {
        *(float2*)p = make_float2(a, b);
    }
    static __device__ __forceinline__ void ld8(const float* p, float* v) {
        float4 a = ((const float4*)p)[0], b = ((const float4*)p)[1];
        v[0] = a.x; v[1] = a.y; v[2] = a.z; v[3] = a.w;
        v[4] = b.x; v[5] = b.y; v[6] = b.z; v[7] = b.w;
    }
    static __device__ __forceinline__ void st8(float* p, const float* v) {
        ((float4*)p)[0] = make_float4(v[0], v[1], v[2], v[3]);
        ((float4*)p)[1] = make_float4(v[4], v[5], v[6], v[7]);
    }
};
template <> struct IOV<ushort> {  // bf16 bits
    static __device__ __forceinline__ float2 ld2(const ushort* p) {
        uint u = *(const uint*)p;
        return make_float2(bf2f((ushort)u), bf2f((ushort)(u >> 16)));
    }
    static __device__ __forceinline__ void st2(ushort* p, float a, float b) {
        *(uint*)p = (uint)f2bf(a) | ((uint)f2bf(b) << 16);
    }
    static __device__ __forceinline__ void ld8(const ushort* p, float* v) {
        uint4 u = *(const uint4*)p;
        v[0] = bf2f((ushort)u.x); v[1] = bf2f((ushort)(u.x >> 16));
        v[2] = bf2f((ushort)u.y); v[3] = bf2f((ushort)(u.y >> 16));
        v[4] = bf2f((ushort)u.z); v[5] = bf2f((ushort)(u.z >> 16));
        v[6] = bf2f((ushort)u.w); v[7] = bf2f((ushort)(u.w >> 16));
    }
    static __device__ __forceinline__ void st8(ushort* p, const float* v) {
        uint4 u;
        u.x = (uint)f2bf(v[0]) | ((uint)f2bf(v[1]) << 16);
        u.y = (uint)f2bf(v[2]) | ((uint)f2bf(v[3]) << 16);
        u.z = (uint)f2bf(v[4]) | ((uint)f2bf(v[5]) << 16);
        u.w = (uint)f2bf(v[6]) | ((uint)f2bf(v[7]) << 16);
        *(uint4*)p = u;
    }
};
template <> struct IOV<unsigned char> {  // fp8 e4m3
    static __device__ __forceinline__ float2 ld2(const unsigned char* p) {
        ushort u = *(const ushort*)p;
        return make_float2(e4m3_dec((unsigned char)u), e4m3_dec((unsigned char)(u >> 8)));
    }
    static __device__ __forceinline__ void st2(unsigned char* p, float a, float b) {
        *(ushort*)p = (ushort)e4m3_enc(a) | ((ushort)e4m3_enc(b) << 8);
    }
    static __device__ __forceinline__ void ld8(const unsigned char* p, float* v) {
        uint2 u = *(const uint2*)p;
#pragma unroll
        for (int j = 0; j < 4; j++) v[j] = e4m3_dec((unsigned char)(u.x >> (8 * j)));
#pragma unroll
        for (int j = 0; j < 4; j++) v[4 + j] = e4m3_dec((unsigned char)(u.y >> (8 * j)));
    }
    static __device__ __forceinline__ void st8(unsigned char* p, const float* v) {
        uint2 u = {0, 0};
#pragma unroll
        for (int j = 0; j < 4; j++) u.x |= (uint)e4m3_enc(v[j]) << (8 * j);
#pragma unroll
        for (int j = 0; j < 4; j++) u.y |= (uint)e4m3_enc(v[4 + j]) << (8 * j);
        *(uint2*)p = u;
    }
};

// ---------------- graph setup ----------------

__global__ void k_count(const int* __restrict__ dst, int* __restrict__ cnt, int E) {
    int e = blockIdx.x * blockDim.x + threadIdx.x;
    if (e < E) atomicAdd(&cnt[dst[e]], 1);
}

// sums PADDED counts (rows padded to multiple of 16)
__global__ void k_scan1(const int* __restrict__ cnt, int* __restrict__ bsum, int N) {
    __shared__ int s[256];
    int i = blockIdx.x * 256 + threadIdx.x;
    s[threadIdx.x] = (i < N) ? ((cnt[i] + 15) & ~15) : 0;
    __syncthreads();
    for (int o = 128; o > 0; o >>= 1) {
        if (threadIdx.x < o) s[threadIdx.x] += s[threadIdx.x + o];
        __syncthreads();
    }
    if (threadIdx.x == 0) bsum[blockIdx.x] = s[0];
}

__global__ void k_scan2(int* __restrict__ bsum, int B) {
    __shared__ int s[1024];
    int t = threadIdx.x;
    int orig = (t < B) ? bsum[t] : 0;
    s[t] = orig;
    __syncthreads();
    for (int o = 1; o < 1024; o <<= 1) {
        int v = (t >= o) ? s[t - o] : 0;
        __syncthreads();
        s[t] += v;
        __syncthreads();
    }
    if (t < B) bsum[t] = s[t] - orig;
}

__global__ void k_scan3(const int* __restrict__ cnt, const int* __restrict__ bsum,
                        int* __restrict__ roff, int* __restrict__ cursor,
                        float* __restrict__ dinv, int N) {
    __shared__ int s[256];
    int i = blockIdx.x * 256 + threadIdx.x;
    int v = (i < N) ? cnt[i] : 0;
    int pv = (v + 15) & ~15;
    s[threadIdx.x] = pv;
    __syncthreads();
    for (int o = 1; o < 256; o <<= 1) {
        int u = (threadIdx.x >= o) ? s[threadIdx.x - o] : 0;
        __syncthreads();
        s[threadIdx.x] += u;
        __syncthreads();
    }
    if (i < N) {
        int off = bsum[blockIdx.x] + s[threadIdx.x] - pv;
        roff[i] = off;
        cursor[i] = off;
        dinv[i] = rsqrtf((float)(v + 1));
        if (i == N - 1) roff[N] = off + pv;
    }
}

__global__ void k_scatter(const int* __restrict__ src, const int* __restrict__ dst,
                          const float* __restrict__ dinv, int* __restrict__ cursor,
                          int2* __restrict__ ev, int E) {
    int e = blockIdx.x * blockDim.x + threadIdx.x;
    if (e < E) {
        int s = src[e], d = dst[e];
        int p = atomicAdd(&cursor[d], 1);
        int2 pk;
        pk.x = s;
        pk.y = __float_as_int(dinv[s] * dinv[d]);
        ev[p] = pk;
    }
}

// fill pad slots with zero-weight self edges
__global__ void k_pad(const int* __restrict__ cursor, const int* __restrict__ roff,
                      int2* __restrict__ ev, int N) {
    int i = blockIdx.x * blockDim.x + threadIdx.x;
    if (i >= N) return;
    int p = cursor[i], e = roff[i + 1];
    int2 pk;
    pk.x = i;
    pk.y = 0;
    for (; p < e; p++) ev[p] = pk;
}

// precompute fragment-ordered bf16 hi/lo for all 17 dense weight matrices
__global__ void k_prepw(const float* __restrict__ Ws1, const float* __restrict__ Ws2,
                        ushort* __restrict__ whi, ushort* __restrict__ wlo) {
    int idx = blockIdx.x * blockDim.x + threadIdx.x;
    if (idx >= 17 * 16384) return;
    int L = idx >> 14, r = idx & 16383;
    int f = r >> 9, e = r & 511, lane = e >> 3, j = e & 7;
    int n = (f >> 2) * 16 + (lane & 15);
    int k = (f & 3) * 32 + (lane >> 4) * 8 + j;
    const float* W = (L < 9) ? (Ws1 + (size_t)L * 16384) : (Ws2 + (size_t)(L - 9) * 16384);
    float w = W[(size_t)k * 128 + n];
    ushort hi = f2bf(w);
    whi[idx] = hi;
    wlo[idx] = f2bf(w - bf2f(hi));
}

// ---------------- sparse ops ----------------

__global__ void k_spmm3(const float* __restrict__ X, const int2* __restrict__ ev,
                        const int* __restrict__ roff, const float* __restrict__ dinv,
                        float* __restrict__ XA, int N) {
    int i = blockIdx.x * blockDim.x + threadIdx.x;
    if (i >= N) return;
    float di = dinv[i];
    float w0 = di * di;
    float a0 = X[(size_t)i * 3 + 0] * w0;
    float a1 = X[(size_t)i * 3 + 1] * w0;
    float a2 = X[(size_t)i * 3 + 2] * w0;
    int je = roff[i + 1];
    for (int j = roff[i]; j < je; j++) {
        int2 e = ev[j];
        float w = __int_as_float(e.y);
        a0 += X[(size_t)e.x * 3 + 0] * w;
        a1 += X[(size_t)e.x * 3 + 1] * w;
        a2 += X[(size_t)e.x * 3 + 2] * w;
    }
    XA[(size_t)i * 3 + 0] = a0;
    XA[(size_t)i * 3 + 1] = a1;
    XA[(size_t)i * 3 + 2] = a2;
}

// Z(pre-BN) = A @ H (H bf16) + fused striped stats.
// 32 rows/block (8 per wave, serial) -> stats atomics 0.8M/dispatch (16ns/atomic
// measured r10->r12: 6.4M->1.6M cut dur 158->80us; this halves again).
// Rows padded to %16 -> branch-free 16-deep gather pipeline per row.
template <typename ZT>
__global__ __launch_bounds__(256) void k_spmm_stats(
    const ushort* __restrict__ H, const int2* __restrict__ ev,
    const int* __restrict__ roff, const float* __restrict__ dinv,
    ZT* __restrict__ Y, float* __restrict__ st, int N) {
    int lane = threadIdx.x & 63, wv = threadIdx.x >> 6;
    const uint* Hu = (const uint*)H;
    float s0 = 0.f, s1 = 0.f, q0 = 0.f, q1 = 0.f;

#pragma unroll
    for (int r = 0; r < 8; r++) {
        int i = blockIdx.x * 32 + wv * 8 + r;
        if (i >= N) break;
        float di = dinv[i];
        float ws = di * di;
        uint u = Hu[(size_t)i * 64 + lane];
        float a0 = bf2f((ushort)u) * ws, a1 = bf2f((ushort)(u >> 16)) * ws;
        int j = roff[i], je = roff[i + 1];
        for (; j < je; j += 16) {
            int2 e[16];
            uint uu[16];
#pragma unroll
            for (int t = 0; t < 16; t++) e[t] = ev[j + t];
#pragma unroll
            for (int t = 0; t < 16; t++) uu[t] = Hu[(size_t)e[t].x * 64 + lane];
#pragma unroll
            for (int t = 0; t < 16; t++) {
                float w = __int_as_float(e[t].y);
                a0 += bf2f((ushort)uu[t]) * w;
                a1 += bf2f((ushort)(uu[t] >> 16)) * w;
            }
        }
        IOV<ZT>::st2(&Y[(size_t)i * 128 + 2 * lane], a0, a1);
        s0 += a0; q0 += a0 * a0;
        s1 += a1; q1 += a1 * a1;
    }

    __shared__ float ls[4][64][4];
    ls[wv][lane][0] = s0; ls[wv][lane][1] = s1;
    ls[wv][lane][2] = q0; ls[wv][lane][3] = q1;
    __syncthreads();
    if (wv == 0) {
        s0 = ls[0][lane][0] + ls[1][lane][0] + ls[2][lane][0] + ls[3][lane][0];
        s1 = ls[0][lane][1] + ls[1][lane][1] + ls[2][lane][1] + ls[3][lane][1];
        q0 = ls[0][lane][2] + ls[1][lane][2] + ls[2][lane][2] + ls[3][lane][2];
        q1 = ls[0][lane][3] + ls[1][lane][3] + ls[2][lane][3] + ls[3][lane][3];
        float* stp = st + (size_t)(blockIdx.x & (NSTRIPE - 1)) * 256;
        atomicAdd(&stp[2 * lane], s0);
        atomicAdd(&stp[2 * lane + 1], s1);
        atomicAdd(&stp[128 + 2 * lane], q0);
        atomicAdd(&stp[129 + 2 * lane], q1);
    }
}

__global__ void k_spmm1(const float* __restrict__ T, const int2* __restrict__ ev,
                        const int* __restrict__ roff, const float* __restrict__ dinv,
                        float* __restrict__ out, int N) {
    int i = blockIdx.x * blockDim.x + threadIdx.x;
    if (i >= N) return;
    float di = dinv[i];
    float a = T[i] * di * di;
    int je = roff[i + 1];
    for (int j = roff[i]; j < je; j++) {
        int2 e = ev[j];
        a += T[e.x] * __int_as_float(e.y);
    }
    out[i] = 1.0f / (1.0f + expf(-a));
}

// finalize striped stats -> affine (for k_dot only)
__global__ void k_bnfin(const float* __restrict__ st, const float* __restrict__ g,
                        const float* __restrict__ b, float* __restrict__ aff, float invN) {
    int c = threadIdx.x;  // 128
    float S = 0.f, Q = 0.f;
    for (int s = 0; s < NSTRIPE; s++) {
        S += st[(size_t)s * 256 + c];
        Q += st[(size_t)s * 256 + 128 + c];
    }
    float m = S * invN;
    float var = Q * invN - m * m;
    float sc = g[c] * rsqrtf(var + EPSV);
    aff[c] = sc;
    aff[128 + c] = b[c] - m * sc;
}

// ---------------- dense ops ----------------

// z(stage0, pre-BN) = (A@x)@W0 with fused striped stats; 32 rows/block (8/wave)
template <typename ZT>
__global__ __launch_bounds__(256) void k_gemm3_stats(
    const float* __restrict__ XA, const float* __restrict__ W0,
    ZT* __restrict__ Y, float* __restrict__ st, int N) {
    int lane = threadIdx.x & 63, wv = threadIdx.x >> 6;
    int c0 = lane * 2;
    float w00 = W0[c0], w10 = W0[128 + c0], w20 = W0[256 + c0];
    float w01 = W0[c0 + 1], w11 = W0[128 + c0 + 1], w21 = W0[256 + c0 + 1];
    float s0 = 0.f, s1 = 0.f, q0 = 0.f, q1 = 0.f;
#pragma unroll
    for (int r = 0; r < 8; r++) {
        int i = blockIdx.x * 32 + wv * 8 + r;
        if (i >= N) break;
        float x0 = XA[(size_t)i * 3], x1 = XA[(size_t)i * 3 + 1], x2 = XA[(size_t)i * 3 + 2];
        float y0 = x0 * w00 + x1 * w10 + x2 * w20;
        float y1 = x0 * w01 + x1 * w11 + x2 * w21;
        IOV<ZT>::st2(&Y[(size_t)i * 128 + c0], y0, y1);
        s0 += y0; q0 += y0 * y0;
        s1 += y1; q1 += y1 * y1;
    }
    __shared__ float ls[4][64][4];
    ls[wv][lane][0] = s0; ls[wv][lane][1] = s1;
    ls[wv][lane][2] = q0; ls[wv][lane][3] = q1;
    __syncthreads();
    if (wv == 0) {
        s0 = ls[0][lane][0] + ls[1][lane][0] + ls[2][lane][0] + ls[3][lane][0];
        s1 = ls[0][lane][1] + ls[1][lane][1] + ls[2][lane][1] + ls[3][lane][1];
        q0 = ls[0][lane][2] + ls[1][lane][2] + ls[2][lane][2] + ls[3][lane][2];
        q1 = ls[0][lane][3] + ls[1][lane][3] + ls[2][lane][3] + ls[3][lane][3];
        float* stp = st + (size_t)(blockIdx.x & (NSTRIPE - 1)) * 256;
        atomicAdd(&stp[2 * lane], s0);
        atomicAdd(&stp[2 * lane + 1], s1);
        atomicAdd(&stp[128 + 2 * lane], q0);
        atomicAdd(&stp[129 + 2 * lane], q1);
    }
}

// H(bf16) = [ReLU(BN(Z)) + skip_in] @ W  (MFMA; fragment-order W hi/lo staging)
template <typename ZT, typename SKT>
__global__ __launch_bounds__(256) void k_gemm_mfma(
    const ZT* __restrict__ Z, const SKT* __restrict__ skip_in, SKT* __restrict__ skip_out,
    const float* __restrict__ st, const float* __restrict__ gz, const float* __restrict__ bz,
    const ushort* __restrict__ whi, const ushort* __restrict__ wlo,
    ushort* __restrict__ H, float invN, int N) {
    __shared__ ushort sW[16384];  // 32 frags x 512 ushorts
    __shared__ float sA[256];
    int tid = threadIdx.x;
    int wave = tid >> 6, lane = tid & 63;
    int l15 = lane & 15, quad = lane >> 4;

    // phase A: striped-stats partial reduce (16 stripes)
    {
        float acc = 0.f;
#pragma unroll
        for (int s = 0; s < NSTRIPE; s++) acc += st[(size_t)s * 256 + tid];
        sA[tid] = acc;
    }
    // phase B: stage W hi (coalesced, fragment-ordered)
    {
        const uint4* src = (const uint4*)whi;
#pragma unroll
        for (int t = 0; t < 8; t++) ((uint4*)sW)[tid + 256 * t] = src[tid + 256 * t];
    }
    __syncthreads();
    // phase C: finalize BN affine
    if (tid < 128) {
        float S = sA[tid], Q = sA[128 + tid];
        float m = S * invN;
        float var = Q * invN - m * m;
        float sc = gz[tid] * rsqrtf(var + EPSV);
        sA[tid] = sc;
        sA[128 + tid] = bz[tid] - m * sc;
    }
    __syncthreads();

    int row = blockIdx.x * 64 + wave * 16 + l15;
    size_t rowc = (size_t)(row < N ? row : N - 1);

    bf16x8 ahi[4];
#pragma unroll
    for (int kc = 0; kc < 4; kc++) {
        int c0 = kc * 32 + quad * 8;
        float v[8];
        IOV<ZT>::ld8(&Z[rowc * 128 + c0], v);
        float av[8];
#pragma unroll
        for (int jj = 0; jj < 8; jj++) {
            float t = v[jj] * sA[c0 + jj] + sA[128 + c0 + jj];
            av[jj] = fmaxf(t, 0.f);
        }
        if (skip_out && row < N) IOV<SKT>::st8(&skip_out[rowc * 128 + c0], av);
        if (skip_in) {
            float w2[8];
            IOV<SKT>::ld8(&skip_in[rowc * 128 + c0], w2);
#pragma unroll
            for (int jj = 0; jj < 8; jj++) av[jj] += w2[jj];
        }
        bf16x8 fh;
#pragma unroll
        for (int jj = 0; jj < 8; jj++) fh[jj] = (__bf16)av[jj];
        ahi[kc] = fh;
    }

    f32x4 acc[8];
#pragma unroll
    for (int ct = 0; ct < 8; ct++) {
        f32x4 z0 = {0.f, 0.f, 0.f, 0.f};
        acc[ct] = z0;
    }

    // pass 1: Ahi * Whi
#pragma unroll
    for (int ct = 0; ct < 8; ct++) {
#pragma unroll
        for (int kc = 0; kc < 4; kc++) {
            bf16x8 b = *(const bf16x8*)&sW[(ct * 4 + kc) * 512 + lane * 8];
            acc[ct] = __builtin_amdgcn_mfma_f32_16x16x32_bf16(ahi[kc], b, acc[ct], 0, 0, 0);
        }
    }
    __syncthreads();
    // stage W lo (coalesced)
    {
        const uint4* src = (const uint4*)wlo;
#pragma unroll
        for (int t = 0; t < 8; t++) ((uint4*)sW)[tid + 256 * t] = src[tid + 256 * t];
    }
    __syncthreads();
    // pass 2: Ahi * Wlo
#pragma unroll
    for (int ct = 0; ct < 8; ct++) {
#pragma unroll
        for (int kc = 0; kc < 4; kc++) {
            bf16x8 b = *(const bf16x8*)&sW[(ct * 4 + kc) * 512 + lane * 8];
            acc[ct] = __builtin_amdgcn_mfma_f32_16x16x32_bf16(ahi[kc], b, acc[ct], 0, 0, 0);
        }
    }
    __syncthreads();
    // epilogue: C layout col=l15, row=quad*4+reg -> LDS -> coalesced bf16 store
    ushort* sC = sW;
#pragma unroll
    for (int ct = 0; ct < 8; ct++)
#pragma unroll
        for (int reg = 0; reg < 4; reg++) {
            int r = wave * 16 + quad * 4 + reg;
            sC[r * 136 + ct * 16 + l15] = f2bf(acc[ct][reg]);
        }
    __syncthreads();
    for (int t = tid; t < 1024; t += 256) {
        int r = t >> 4, c4 = t & 15;
        int grow = blockIdx.x * 64 + r;
        if (grow < N)
            ((uint4*)(H + (size_t)grow * 128))[c4] = *(const uint4*)&sC[r * 136 + c4 * 8];
    }
}

// t = [ReLU(BN(Z)) + skip0(post-act)] @ Wout  (wave per row; affine precomputed)
template <typename ZT, typename SKT>
__global__ __launch_bounds__(256) void k_dot(
    const ZT* __restrict__ Z, const SKT* __restrict__ S0,
    const float* __restrict__ aff, const float* __restrict__ Wout,
    float* __restrict__ T, int N) {
    int i = blockIdx.x * 4 + (threadIdx.x >> 6);
    if (i >= N) return;
    int lane = threadIdx.x & 63;
    int c0 = 2 * lane, c1 = c0 + 1;
    float2 z = IOV<ZT>::ld2(&Z[(size_t)i * 128 + c0]);
    float2 s = IOV<SKT>::ld2(&S0[(size_t)i * 128 + c0]);
    float p0 = fmaxf(z.x * aff[c0] + aff[128 + c0], 0.f) + s.x;
    float p1 = fmaxf(z.y * aff[c1] + aff[128 + c1], 0.f) + s.y;
    float a = p0 * Wout[c0] + p1 * Wout[c1];
    for (int o = 32; o > 0; o >>= 1) a += __shfl_down(a, o);
    if (lane == 0) T[i] = a;
}

// ---------------- templated pipeline ----------------

template <typename ZT, typename SKT>
static void run_all(const float* x, const int* src, const int* dst, const float* W0,
                    const float* Ws1, const float* g1, const float* b1,
                    const float* Ws2, const float* g2, const float* b2,
                    const float* Wout, float* out, char* ws, int N, int E,
                    hipStream_t stream) {
    char* p = ws;
    auto alloc = [&](size_t bytes) -> void* {
        void* r = (void*)p;
        p += (bytes + 255) & ~(size_t)255;
        return r;
    };
    size_t Epad = (size_t)E + 15 * (size_t)N + 16;
    int*   roff   = (int*)alloc((size_t)(N + 1) * 4);
    float* dinv   = (float*)alloc((size_t)N * 4);
    int2*  ev     = (int2*)alloc(Epad * 8);
    int*   bsum   = (int*)alloc(4096);
    float* st_all = (float*)alloc((size_t)18 * NSTRIPE * 256 * 4);
    float* aff    = (float*)alloc(1024);
    ushort* whi   = (ushort*)alloc((size_t)17 * 16384 * 2);
    ushort* wlo   = (ushort*)alloc((size_t)17 * 16384 * 2);
    size_t nz = (size_t)N * 128;
    ushort* hb = (ushort*)alloc(nz * 2);
    ZT* zb = (ZT*)alloc(nz * sizeof(ZT));
    SKT* skips = (SKT*)alloc((size_t)9 * nz * sizeof(SKT));
    auto skip = [&](int s) { return skips + (size_t)s * nz; };
    auto stg  = [&](int s) { return st_all + (size_t)s * NSTRIPE * 256; };

    // lifetime-disjoint aliases
    int* cnt    = (int*)skip(8);
    int* cursor = (int*)((char*)skip(8) + (((size_t)N * 4 + 255) & ~(size_t)255));
    float* xa   = (float*)hb;
    float* tbuf = (float*)hb;

    float invN = 1.0f / (float)N;
    auto gb = [&](int stage, const float** g, const float** b) {
        if (stage <= 9) { *g = g1 + (size_t)stage * 128; *b = b1 + (size_t)stage * 128; }
        else { *g = g2 + (size_t)(stage - 10) * 128; *b = b2 + (size_t)(stage - 10) * 128; }
    };

    // --- setup: CSR (padded to %16) + weight prep ---
    hipMemsetAsync(st_all, 0, (size_t)18 * NSTRIPE * 256 * 4, stream);
    hipMemsetAsync(cnt, 0, (size_t)N * 4, stream);
    k_count<<<(E + 255) / 256, 256, 0, stream>>>(dst, cnt, E);
    int B = (N + 255) / 256;
    k_scan1<<<B, 256, 0, stream>>>(cnt, bsum, N);
    k_scan2<<<1, 1024, 0, stream>>>(bsum, B);
    k_scan3<<<B, 256, 0, stream>>>(cnt, bsum, roff, cursor, dinv, N);
    k_scatter<<<(E + 255) / 256, 256, 0, stream>>>(src, dst, dinv, cursor, ev, E);
    k_pad<<<(N + 255) / 256, 256, 0, stream>>>(cursor, roff, ev, N);
    k_prepw<<<(17 * 16384 + 255) / 256, 256, 0, stream>>>(Ws1, Ws2, whi, wlo);

    int gg = (N + 63) / 64;
    int gs4 = (N + 3) / 4;
    int gs32 = (N + 31) / 32;

    // --- layer 0: z = (A@x)@W0 (pre-BN) + fused stats ---
    k_spmm3<<<(N + 255) / 256, 256, 0, stream>>>(x, ev, roff, dinv, xa, N);
    k_gemm3_stats<ZT><<<gs32, 256, 0, stream>>>(xa, W0, zb, stg(0), N);

    // --- down layers 1..9 ---
    for (int l = 1; l <= 9; l++) {
        const float *gzp, *bzp;
        gb(l - 1, &gzp, &bzp);
        k_gemm_mfma<ZT, SKT><<<gg, 256, 0, stream>>>(
            zb, (const SKT*)nullptr, skip(l - 1), stg(l - 1), gzp, bzp,
            whi + (size_t)(l - 1) * 16384, wlo + (size_t)(l - 1) * 16384, hb, invN, N);
        k_spmm_stats<ZT><<<gs32, 256, 0, stream>>>(hb, ev, roff, dinv, zb, stg(l), N);
    }

    // --- up layers 0..7 ---
    for (int i = 0; i < 8; i++) {
        int zs = 9 + i;
        const float *gzp, *bzp;
        gb(zs, &gzp, &bzp);
        k_gemm_mfma<ZT, SKT><<<gg, 256, 0, stream>>>(
            zb, skip(8 - i), (SKT*)nullptr, stg(zs), gzp, bzp,
            whi + (size_t)(9 + i) * 16384, wlo + (size_t)(9 + i) * 16384, hb, invN, N);
        k_spmm_stats<ZT><<<gs32, 256, 0, stream>>>(hb, ev, roff, dinv, zb, stg(10 + i), N);
    }

    // --- output: sigmoid(A @ ([act17(z) + skip0] @ Wout)) ---
    const float *gzp, *bzp;
    gb(17, &gzp, &bzp);
    k_bnfin<<<1, 128, 0, stream>>>(stg(17), gzp, bzp, aff, invN);
    k_dot<ZT, SKT><<<gs4, 256, 0, stream>>>(zb, skip(0), aff, Wout, tbuf, N);
    k_spmm1<<<(N + 255) / 256, 256, 0, stream>>>(tbuf, ev, roff, dinv, out, N);
}

// ---------------- launch ----------------

extern "C" void kernel_launch(void* const* d_in, const int* in_sizes, int n_in,
                              void* d_out, int out_size, void* d_ws, size_t ws_size,
                              hipStream_t stream) {
    const float* x    = (const float*)d_in[0];
    const int*   ei   = (const int*)d_in[1];
    const float* W0   = (const float*)d_in[2];
    const float* Ws1  = (const float*)d_in[3];
    const float* g1   = (const float*)d_in[4];
    const float* b1   = (const float*)d_in[5];
    const float* Ws2  = (const float*)d_in[6];
    const float* g2   = (const float*)d_in[7];
    const float* b2   = (const float*)d_in[8];
    const float* Wout = (const float*)d_in[9];
    float* out = (float*)d_out;

    int N = in_sizes[0] / 3;
    int E = in_sizes[1] / 2;
    const int* src = ei;
    const int* dst = ei + E;

    size_t nz = (size_t)N * 128;
    size_t Epad = (size_t)E + 15 * (size_t)N + 16;
    auto need = [&](size_t zbytes, size_t skbytes) -> size_t {
        size_t t = 0;
        auto add = [&](size_t b) { t += (b + 255) & ~(size_t)255; };
        add((size_t)(N + 1) * 4);
        add((size_t)N * 4);
        add(Epad * 8);
        add(4096);
        add((size_t)18 * NSTRIPE * 256 * 4);
        add(1024);
        add((size_t)17 * 16384 * 2);
        add((size_t)17 * 16384 * 2);
        add(nz * 2);
        add(nz * zbytes);
        add((size_t)9 * nz * skbytes);
        return t;
    };

    char* ws = (char*)d_ws;
    if (need(4, 2) <= ws_size)          // fp32 z, bf16 skips (~341 MB)
        run_all<float, ushort>(x, src, dst, W0, Ws1, g1, b1, Ws2, g2, b2, Wout, out, ws, N, E, stream);
    else if (need(4, 1) <= ws_size)     // fp32 z, fp8 skips (~225 MB)
        run_all<float, unsigned char>(x, src, dst, W0, Ws1, g1, b1, Ws2, g2, b2, Wout, out, ws, N, E, stream);
    else                                // bf16 z, fp8 skips (~199 MB)
        run_all<ushort, unsigned char>(x, src, dst, W0, Ws1, g1, b1, Ws2, g2, b2, Wout, out, ws, N, E, stream);
}

// Round 15
// 2064.365 us; speedup vs baseline: 1.2810x; 1.0303x over previous
//
#include <hip/hip_runtime.h>
#include <hip/hip_bf16.h>

#define EPSV 1e-5f
#define NSTRIPE 16

typedef unsigned int uint;
typedef unsigned short ushort;
typedef __attribute__((ext_vector_type(8))) __bf16 bf16x8;
typedef __attribute__((ext_vector_type(4))) float f32x4;

static __device__ __forceinline__ float bf2f(ushort u) {
    return __uint_as_float(((uint)u) << 16);
}
static __device__ __forceinline__ ushort f2bf(float f) {
    __hip_bfloat16 h = __float2bfloat16(f);
    return __builtin_bit_cast(ushort, h);
}

// ---------------- fp8 e4m3 codec (low-mem skip tier) ----------------

static __device__ __forceinline__ float e4m3_dec(unsigned char b) {
    int s = b >> 7, E = (b >> 3) & 15, m = b & 7;
    float v = (E == 0) ? (float)m * 0.001953125f
                       : (float)(8 + m) * 0.125f * exp2f((float)(E - 7));
    return s ? -v : v;
}
static __device__ __forceinline__ unsigned char e4m3_enc(float f) {
    unsigned su = (__float_as_uint(f) >> 24) & 0x80u;
    float a = fabsf(f);
    if (!(a < 448.f)) return (unsigned char)(su | 0x7E);
    if (a < 0.015625f) {
        int m = (int)rintf(a * 512.f);
        return (unsigned char)(su | (m >= 8 ? 0x08 : m));
    }
    int e;
    frexpf(a, &e);
    int E = e - 1 + 7;
    float mant = a * exp2f((float)(1 - e)) - 1.0f;
    int mi = (int)rintf(mant * 8.f);
    if (mi >= 8) { mi = 0; E++; }
    if (E >= 16) return (unsigned char)(su | 0x7E);
    if (E == 15 && mi == 7) mi = 6;
    return (unsigned char)(su | (E << 3) | mi);
}

// ---------------- storage traits ----------------

template <typename T> struct IOV;
template <> struct IOV<float> {
    static __device__ __forceinline__ float2 ld2(const float* p) { return *(const float2*)p; }
    static __device__ __forceinline__ void st2(float* p, float a, float b) {
        *(float2*)p = make_float2(a, b);
    }
    static __device__ __forceinline__ void ld8(const float* p, float* v) {
        float4 a = ((const float4*)p)[0], b = ((const float4*)p)[1];
        v[0] = a.x; v[1] = a.y; v[2] = a.z; v[3] = a.w;
        v[4] = b.x; v[5] = b.y; v[6] = b.z; v[7] = b.w;
    }
    static __device__ __forceinline__ void st8(float* p, const float* v) {
        ((float4*)p)[0] = make_float4(v[0], v[1], v[2], v[3]);
        ((float4*)p)[1] = make_float4(v[4], v[5], v[6], v[7]);
    }
};
template <> struct IOV<ushort> {  // bf16 bits
    static __device__ __forceinline__ float2 ld2(const ushort* p) {
        uint u = *(const uint*)p;
        return make_float2(bf2f((ushort)u), bf2f((ushort)(u >> 16)));
    }
    static __device__ __forceinline__ void st2(ushort* p, float a, float b) {
        *(uint*)p = (uint)f2bf(a) | ((uint)f2bf(b) << 16);
    }
    static __device__ __forceinline__ void ld8(const ushort* p, float* v) {
        uint4 u = *(const uint4*)p;
        v[0] = bf2f((ushort)u.x); v[1] = bf2f((ushort)(u.x >> 16));
        v[2] = bf2f((ushort)u.y); v[3] = bf2f((ushort)(u.y >> 16));
        v[4] = bf2f((ushort)u.z); v[5] = bf2f((ushort)(u.z >> 16));
        v[6] = bf2f((ushort)u.w); v[7] = bf2f((ushort)(u.w >> 16));
    }
    static __device__ __forceinline__ void st8(ushort* p, const float* v) {
        uint4 u;
        u.x = (uint)f2bf(v[0]) | ((uint)f2bf(v[1]) << 16);
        u.y = (uint)f2bf(v[2]) | ((uint)f2bf(v[3]) << 16);
        u.z = (uint)f2bf(v[4]) | ((uint)f2bf(v[5]) << 16);
        u.w = (uint)f2bf(v[6]) | ((uint)f2bf(v[7]) << 16);
        *(uint4*)p = u;
    }
};
template <> struct IOV<unsigned char> {  // fp8 e4m3
    static __device__ __forceinline__ float2 ld2(const unsigned char* p) {
        ushort u = *(const ushort*)p;
        return make_float2(e4m3_dec((unsigned char)u), e4m3_dec((unsigned char)(u >> 8)));
    }
    static __device__ __forceinline__ void st2(unsigned char* p, float a, float b) {
        *(ushort*)p = (ushort)e4m3_enc(a) | ((ushort)e4m3_enc(b) << 8);
    }
    static __device__ __forceinline__ void ld8(const unsigned char* p, float* v) {
        uint2 u = *(const uint2*)p;
#pragma unroll
        for (int j = 0; j < 4; j++) v[j] = e4m3_dec((unsigned char)(u.x >> (8 * j)));
#pragma unroll
        for (int j = 0; j < 4; j++) v[4 + j] = e4m3_dec((unsigned char)(u.y >> (8 * j)));
    }
    static __device__ __forceinline__ void st8(unsigned char* p, const float* v) {
        uint2 u = {0, 0};
#pragma unroll
        for (int j = 0; j < 4; j++) u.x |= (uint)e4m3_enc(v[j]) << (8 * j);
#pragma unroll
        for (int j = 0; j < 4; j++) u.y |= (uint)e4m3_enc(v[4 + j]) << (8 * j);
        *(uint2*)p = u;
    }
};

// ---------------- graph setup ----------------

__global__ void k_count(const int* __restrict__ dst, int* __restrict__ cnt, int E) {
    int e = blockIdx.x * blockDim.x + threadIdx.x;
    if (e < E) atomicAdd(&cnt[dst[e]], 1);
}

// sums PADDED counts (rows padded to multiple of 16)
__global__ void k_scan1(const int* __restrict__ cnt, int* __restrict__ bsum, int N) {
    __shared__ int s[256];
    int i = blockIdx.x * 256 + threadIdx.x;
    s[threadIdx.x] = (i < N) ? ((cnt[i] + 15) & ~15) : 0;
    __syncthreads();
    for (int o = 128; o > 0; o >>= 1) {
        if (threadIdx.x < o) s[threadIdx.x] += s[threadIdx.x + o];
        __syncthreads();
    }
    if (threadIdx.x == 0) bsum[blockIdx.x] = s[0];
}

__global__ void k_scan2(int* __restrict__ bsum, int B) {
    __shared__ int s[1024];
    int t = threadIdx.x;
    int orig = (t < B) ? bsum[t] : 0;
    s[t] = orig;
    __syncthreads();
    for (int o = 1; o < 1024; o <<= 1) {
        int v = (t >= o) ? s[t - o] : 0;
        __syncthreads();
        s[t] += v;
        __syncthreads();
    }
    if (t < B) bsum[t] = s[t] - orig;
}

__global__ void k_scan3(const int* __restrict__ cnt, const int* __restrict__ bsum,
                        int* __restrict__ roff, int* __restrict__ cursor,
                        float* __restrict__ dinv, int N) {
    __shared__ int s[256];
    int i = blockIdx.x * 256 + threadIdx.x;
    int v = (i < N) ? cnt[i] : 0;
    int pv = (v + 15) & ~15;
    s[threadIdx.x] = pv;
    __syncthreads();
    for (int o = 1; o < 256; o <<= 1) {
        int u = (threadIdx.x >= o) ? s[threadIdx.x - o] : 0;
        __syncthreads();
        s[threadIdx.x] += u;
        __syncthreads();
    }
    if (i < N) {
        int off = bsum[blockIdx.x] + s[threadIdx.x] - pv;
        roff[i] = off;
        cursor[i] = off;
        dinv[i] = rsqrtf((float)(v + 1));
        if (i == N - 1) roff[N] = off + pv;
    }
}

__global__ void k_scatter(const int* __restrict__ src, const int* __restrict__ dst,
                          const float* __restrict__ dinv, int* __restrict__ cursor,
                          int2* __restrict__ ev, int E) {
    int e = blockIdx.x * blockDim.x + threadIdx.x;
    if (e < E) {
        int s = src[e], d = dst[e];
        int p = atomicAdd(&cursor[d], 1);
        int2 pk;
        pk.x = s;
        pk.y = __float_as_int(dinv[s] * dinv[d]);
        ev[p] = pk;
    }
}

// fill pad slots with zero-weight self edges
__global__ void k_pad(const int* __restrict__ cursor, const int* __restrict__ roff,
                      int2* __restrict__ ev, int N) {
    int i = blockIdx.x * blockDim.x + threadIdx.x;
    if (i >= N) return;
    int p = cursor[i], e = roff[i + 1];
    int2 pk;
    pk.x = i;
    pk.y = 0;
    for (; p < e; p++) ev[p] = pk;
}

// precompute fragment-ordered bf16 hi/lo for all 17 dense weight matrices
__global__ void k_prepw(const float* __restrict__ Ws1, const float* __restrict__ Ws2,
                        ushort* __restrict__ whi, ushort* __restrict__ wlo) {
    int idx = blockIdx.x * blockDim.x + threadIdx.x;
    if (idx >= 17 * 16384) return;
    int L = idx >> 14, r = idx & 16383;
    int f = r >> 9, e = r & 511, lane = e >> 3, j = e & 7;
    int n = (f >> 2) * 16 + (lane & 15);
    int k = (f & 3) * 32 + (lane >> 4) * 8 + j;
    const float* W = (L < 9) ? (Ws1 + (size_t)L * 16384) : (Ws2 + (size_t)(L - 9) * 16384);
    float w = W[(size_t)k * 128 + n];
    ushort hi = f2bf(w);
    whi[idx] = hi;
    wlo[idx] = f2bf(w - bf2f(hi));
}

// ---------------- sparse ops ----------------

__global__ void k_spmm3(const float* __restrict__ X, const int2* __restrict__ ev,
                        const int* __restrict__ roff, const float* __restrict__ dinv,
                        float* __restrict__ XA, int N) {
    int i = blockIdx.x * blockDim.x + threadIdx.x;
    if (i >= N) return;
    float di = dinv[i];
    float w0 = di * di;
    float a0 = X[(size_t)i * 3 + 0] * w0;
    float a1 = X[(size_t)i * 3 + 1] * w0;
    float a2 = X[(size_t)i * 3 + 2] * w0;
    int je = roff[i + 1];
    for (int j = roff[i]; j < je; j++) {
        int2 e = ev[j];
        float w = __int_as_float(e.y);
        a0 += X[(size_t)e.x * 3 + 0] * w;
        a1 += X[(size_t)e.x * 3 + 1] * w;
        a2 += X[(size_t)e.x * 3 + 2] * w;
    }
    XA[(size_t)i * 3 + 0] = a0;
    XA[(size_t)i * 3 + 1] = a1;
    XA[(size_t)i * 3 + 2] = a2;
}

// Z(pre-BN) = A @ H (H bf16) + fused striped stats.
// 32 rows/block (8 per wave, serial); 8-deep gather batch (16-deep bloated VGPR
// to 52 -> occupancy 35%; 8-deep was measured equal per-iter and frees ~12 regs).
template <typename ZT>
__global__ __launch_bounds__(256) void k_spmm_stats(
    const ushort* __restrict__ H, const int2* __restrict__ ev,
    const int* __restrict__ roff, const float* __restrict__ dinv,
    ZT* __restrict__ Y, float* __restrict__ st, int N) {
    int lane = threadIdx.x & 63, wv = threadIdx.x >> 6;
    const uint* Hu = (const uint*)H;
    float s0 = 0.f, s1 = 0.f, q0 = 0.f, q1 = 0.f;

#pragma unroll
    for (int r = 0; r < 8; r++) {
        int i = blockIdx.x * 32 + wv * 8 + r;
        if (i >= N) break;
        float di = dinv[i];
        float ws = di * di;
        uint u = Hu[(size_t)i * 64 + lane];
        float a0 = bf2f((ushort)u) * ws, a1 = bf2f((ushort)(u >> 16)) * ws;
        int j = roff[i], je = roff[i + 1];
        for (; j < je; j += 8) {
            int2 e[8];
            uint uu[8];
#pragma unroll
            for (int t = 0; t < 8; t++) e[t] = ev[j + t];
#pragma unroll
            for (int t = 0; t < 8; t++) uu[t] = Hu[(size_t)e[t].x * 64 + lane];
#pragma unroll
            for (int t = 0; t < 8; t++) {
                float w = __int_as_float(e[t].y);
                a0 += bf2f((ushort)uu[t]) * w;
                a1 += bf2f((ushort)(uu[t] >> 16)) * w;
            }
        }
        IOV<ZT>::st2(&Y[(size_t)i * 128 + 2 * lane], a0, a1);
        s0 += a0; q0 += a0 * a0;
        s1 += a1; q1 += a1 * a1;
    }

    __shared__ float ls[4][64][4];
    ls[wv][lane][0] = s0; ls[wv][lane][1] = s1;
    ls[wv][lane][2] = q0; ls[wv][lane][3] = q1;
    __syncthreads();
    if (wv == 0) {
        s0 = ls[0][lane][0] + ls[1][lane][0] + ls[2][lane][0] + ls[3][lane][0];
        s1 = ls[0][lane][1] + ls[1][lane][1] + ls[2][lane][1] + ls[3][lane][1];
        q0 = ls[0][lane][2] + ls[1][lane][2] + ls[2][lane][2] + ls[3][lane][2];
        q1 = ls[0][lane][3] + ls[1][lane][3] + ls[2][lane][3] + ls[3][lane][3];
        float* stp = st + (size_t)(blockIdx.x & (NSTRIPE - 1)) * 256;
        atomicAdd(&stp[2 * lane], s0);
        atomicAdd(&stp[2 * lane + 1], s1);
        atomicAdd(&stp[128 + 2 * lane], q0);
        atomicAdd(&stp[129 + 2 * lane], q1);
    }
}

__global__ void k_spmm1(const float* __restrict__ T, const int2* __restrict__ ev,
                        const int* __restrict__ roff, const float* __restrict__ dinv,
                        float* __restrict__ out, int N) {
    int i = blockIdx.x * blockDim.x + threadIdx.x;
    if (i >= N) return;
    float di = dinv[i];
    float a = T[i] * di * di;
    int je = roff[i + 1];
    for (int j = roff[i]; j < je; j++) {
        int2 e = ev[j];
        a += T[e.x] * __int_as_float(e.y);
    }
    out[i] = 1.0f / (1.0f + expf(-a));
}

// finalize striped stats -> affine (for k_dot only)
__global__ void k_bnfin(const float* __restrict__ st, const float* __restrict__ g,
                        const float* __restrict__ b, float* __restrict__ aff, float invN) {
    int c = threadIdx.x;  // 128
    float S = 0.f, Q = 0.f;
    for (int s = 0; s < NSTRIPE; s++) {
        S += st[(size_t)s * 256 + c];
        Q += st[(size_t)s * 256 + 128 + c];
    }
    float m = S * invN;
    float var = Q * invN - m * m;
    float sc = g[c] * rsqrtf(var + EPSV);
    aff[c] = sc;
    aff[128 + c] = b[c] - m * sc;
}

// ---------------- dense ops ----------------

// z(stage0, pre-BN) = (A@x)@W0 with fused striped stats; 32 rows/block (8/wave)
template <typename ZT>
__global__ __launch_bounds__(256) void k_gemm3_stats(
    const float* __restrict__ XA, const float* __restrict__ W0,
    ZT* __restrict__ Y, float* __restrict__ st, int N) {
    int lane = threadIdx.x & 63, wv = threadIdx.x >> 6;
    int c0 = lane * 2;
    float w00 = W0[c0], w10 = W0[128 + c0], w20 = W0[256 + c0];
    float w01 = W0[c0 + 1], w11 = W0[128 + c0 + 1], w21 = W0[256 + c0 + 1];
    float s0 = 0.f, s1 = 0.f, q0 = 0.f, q1 = 0.f;
#pragma unroll
    for (int r = 0; r < 8; r++) {
        int i = blockIdx.x * 32 + wv * 8 + r;
        if (i >= N) break;
        float x0 = XA[(size_t)i * 3], x1 = XA[(size_t)i * 3 + 1], x2 = XA[(size_t)i * 3 + 2];
        float y0 = x0 * w00 + x1 * w10 + x2 * w20;
        float y1 = x0 * w01 + x1 * w11 + x2 * w21;
        IOV<ZT>::st2(&Y[(size_t)i * 128 + c0], y0, y1);
        s0 += y0; q0 += y0 * y0;
        s1 += y1; q1 += y1 * y1;
    }
    __shared__ float ls[4][64][4];
    ls[wv][lane][0] = s0; ls[wv][lane][1] = s1;
    ls[wv][lane][2] = q0; ls[wv][lane][3] = q1;
    __syncthreads();
    if (wv == 0) {
        s0 = ls[0][lane][0] + ls[1][lane][0] + ls[2][lane][0] + ls[3][lane][0];
        s1 = ls[0][lane][1] + ls[1][lane][1] + ls[2][lane][1] + ls[3][lane][1];
        q0 = ls[0][lane][2] + ls[1][lane][2] + ls[2][lane][2] + ls[3][lane][2];
        q1 = ls[0][lane][3] + ls[1][lane][3] + ls[2][lane][3] + ls[3][lane][3];
        float* stp = st + (size_t)(blockIdx.x & (NSTRIPE - 1)) * 256;
        atomicAdd(&stp[2 * lane], s0);
        atomicAdd(&stp[2 * lane + 1], s1);
        atomicAdd(&stp[128 + 2 * lane], q0);
        atomicAdd(&stp[129 + 2 * lane], q1);
    }
}

// H(bf16) = [ReLU(BN(Z)) + skip_in] @ W  (MFMA; fragment-order W hi/lo staging)
template <typename ZT, typename SKT>
__global__ __launch_bounds__(256) void k_gemm_mfma(
    const ZT* __restrict__ Z, const SKT* __restrict__ skip_in, SKT* __restrict__ skip_out,
    const float* __restrict__ st, const float* __restrict__ gz, const float* __restrict__ bz,
    const ushort* __restrict__ whi, const ushort* __restrict__ wlo,
    ushort* __restrict__ H, float invN, int N) {
    __shared__ ushort sW[16384];  // 32 frags x 512 ushorts
    __shared__ float sA[256];
    int tid = threadIdx.x;
    int wave = tid >> 6, lane = tid & 63;
    int l15 = lane & 15, quad = lane >> 4;

    // phase A: striped-stats partial reduce (16 stripes)
    {
        float acc = 0.f;
#pragma unroll
        for (int s = 0; s < NSTRIPE; s++) acc += st[(size_t)s * 256 + tid];
        sA[tid] = acc;
    }
    // phase B: stage W hi (coalesced, fragment-ordered)
    {
        const uint4* src = (const uint4*)whi;
#pragma unroll
        for (int t = 0; t < 8; t++) ((uint4*)sW)[tid + 256 * t] = src[tid + 256 * t];
    }
    __syncthreads();
    // phase C: finalize BN affine
    if (tid < 128) {
        float S = sA[tid], Q = sA[128 + tid];
        float m = S * invN;
        float var = Q * invN - m * m;
        float sc = gz[tid] * rsqrtf(var + EPSV);
        sA[tid] = sc;
        sA[128 + tid] = bz[tid] - m * sc;
    }
    __syncthreads();

    int row = blockIdx.x * 64 + wave * 16 + l15;
    size_t rowc = (size_t)(row < N ? row : N - 1);

    bf16x8 ahi[4];
#pragma unroll
    for (int kc = 0; kc < 4; kc++) {
        int c0 = kc * 32 + quad * 8;
        float v[8];
        IOV<ZT>::ld8(&Z[rowc * 128 + c0], v);
        float av[8];
#pragma unroll
        for (int jj = 0; jj < 8; jj++) {
            float t = v[jj] * sA[c0 + jj] + sA[128 + c0 + jj];
            av[jj] = fmaxf(t, 0.f);
        }
        if (skip_out && row < N) IOV<SKT>::st8(&skip_out[rowc * 128 + c0], av);
        if (skip_in) {
            float w2[8];
            IOV<SKT>::ld8(&skip_in[rowc * 128 + c0], w2);
#pragma unroll
            for (int jj = 0; jj < 8; jj++) av[jj] += w2[jj];
        }
        bf16x8 fh;
#pragma unroll
        for (int jj = 0; jj < 8; jj++) fh[jj] = (__bf16)av[jj];
        ahi[kc] = fh;
    }

    f32x4 acc[8];
#pragma unroll
    for (int ct = 0; ct < 8; ct++) {
        f32x4 z0 = {0.f, 0.f, 0.f, 0.f};
        acc[ct] = z0;
    }

    // pass 1: Ahi * Whi
#pragma unroll
    for (int ct = 0; ct < 8; ct++) {
#pragma unroll
        for (int kc = 0; kc < 4; kc++) {
            bf16x8 b = *(const bf16x8*)&sW[(ct * 4 + kc) * 512 + lane * 8];
            acc[ct] = __builtin_amdgcn_mfma_f32_16x16x32_bf16(ahi[kc], b, acc[ct], 0, 0, 0);
        }
    }
    __syncthreads();
    // stage W lo (coalesced)
    {
        const uint4* src = (const uint4*)wlo;
#pragma unroll
        for (int t = 0; t < 8; t++) ((uint4*)sW)[tid + 256 * t] = src[tid + 256 * t];
    }
    __syncthreads();
    // pass 2: Ahi * Wlo
#pragma unroll
    for (int ct = 0; ct < 8; ct++) {
#pragma unroll
        for (int kc = 0; kc < 4; kc++) {
            bf16x8 b = *(const bf16x8*)&sW[(ct * 4 + kc) * 512 + lane * 8];
            acc[ct] = __builtin_amdgcn_mfma_f32_16x16x32_bf16(ahi[kc], b, acc[ct], 0, 0, 0);
        }
    }
    __syncthreads();
    // epilogue: C layout col=l15, row=quad*4+reg -> LDS -> coalesced bf16 store
    ushort* sC = sW;
#pragma unroll
    for (int ct = 0; ct < 8; ct++)
#pragma unroll
        for (int reg = 0; reg < 4; reg++) {
            int r = wave * 16 + quad * 4 + reg;
            sC[r * 136 + ct * 16 + l15] = f2bf(acc[ct][reg]);
        }
    __syncthreads();
    for (int t = tid; t < 1024; t += 256) {
        int r = t >> 4, c4 = t & 15;
        int grow = blockIdx.x * 64 + r;
        if (grow < N)
            ((uint4*)(H + (size_t)grow * 128))[c4] = *(const uint4*)&sC[r * 136 + c4 * 8];
    }
}

// t = [ReLU(BN(Z)) + skip0(post-act)] @ Wout  (wave per row; affine precomputed)
template <typename ZT, typename SKT>
__global__ __launch_bounds__(256) void k_dot(
    const ZT* __restrict__ Z, const SKT* __restrict__ S0,
    const float* __restrict__ aff, const float* __restrict__ Wout,
    float* __restrict__ T, int N) {
    int i = blockIdx.x * 4 + (threadIdx.x >> 6);
    if (i >= N) return;
    int lane = threadIdx.x & 63;
    int c0 = 2 * lane, c1 = c0 + 1;
    float2 z = IOV<ZT>::ld2(&Z[(size_t)i * 128 + c0]);
    float2 s = IOV<SKT>::ld2(&S0[(size_t)i * 128 + c0]);
    float p0 = fmaxf(z.x * aff[c0] + aff[128 + c0], 0.f) + s.x;
    float p1 = fmaxf(z.y * aff[c1] + aff[128 + c1], 0.f) + s.y;
    float a = p0 * Wout[c0] + p1 * Wout[c1];
    for (int o = 32; o > 0; o >>= 1) a += __shfl_down(a, o);
    if (lane == 0) T[i] = a;
}

// ---------------- templated pipeline ----------------

template <typename ZT, typename SKT>
static void run_all(const float* x, const int* src, const int* dst, const float* W0,
                    const float* Ws1, const float* g1, const float* b1,
                    const float* Ws2, const float* g2, const float* b2,
                    const float* Wout, float* out, char* ws, int N, int E,
                    hipStream_t stream) {
    char* p = ws;
    auto alloc = [&](size_t bytes) -> void* {
        void* r = (void*)p;
        p += (bytes + 255) & ~(size_t)255;
        return r;
    };
    size_t Epad = (size_t)E + 15 * (size_t)N + 16;
    int*   roff   = (int*)alloc((size_t)(N + 1) * 4);
    float* dinv   = (float*)alloc((size_t)N * 4);
    int2*  ev     = (int2*)alloc(Epad * 8);
    int*   bsum   = (int*)alloc(4096);
    float* st_all = (float*)alloc((size_t)18 * NSTRIPE * 256 * 4);
    float* aff    = (float*)alloc(1024);
    ushort* whi   = (ushort*)alloc((size_t)17 * 16384 * 2);
    ushort* wlo   = (ushort*)alloc((size_t)17 * 16384 * 2);
    size_t nz = (size_t)N * 128;
    ushort* hb = (ushort*)alloc(nz * 2);
    ZT* zb = (ZT*)alloc(nz * sizeof(ZT));
    SKT* skips = (SKT*)alloc((size_t)9 * nz * sizeof(SKT));
    auto skip = [&](int s) { return skips + (size_t)s * nz; };
    auto stg  = [&](int s) { return st_all + (size_t)s * NSTRIPE * 256; };

    // lifetime-disjoint aliases
    int* cnt    = (int*)skip(8);
    int* cursor = (int*)((char*)skip(8) + (((size_t)N * 4 + 255) & ~(size_t)255));
    float* xa   = (float*)hb;
    float* tbuf = (float*)hb;

    float invN = 1.0f / (float)N;
    auto gb = [&](int stage, const float** g, const float** b) {
        if (stage <= 9) { *g = g1 + (size_t)stage * 128; *b = b1 + (size_t)stage * 128; }
        else { *g = g2 + (size_t)(stage - 10) * 128; *b = b2 + (size_t)(stage - 10) * 128; }
    };

    // --- setup: CSR (padded to %16) + weight prep ---
    hipMemsetAsync(st_all, 0, (size_t)18 * NSTRIPE * 256 * 4, stream);
    hipMemsetAsync(cnt, 0, (size_t)N * 4, stream);
    k_count<<<(E + 255) / 256, 256, 0, stream>>>(dst, cnt, E);
    int B = (N + 255) / 256;
    k_scan1<<<B, 256, 0, stream>>>(cnt, bsum, N);
    k_scan2<<<1, 1024, 0, stream>>>(bsum, B);
    k_scan3<<<B, 256, 0, stream>>>(cnt, bsum, roff, cursor, dinv, N);
    k_scatter<<<(E + 255) / 256, 256, 0, stream>>>(src, dst, dinv, cursor, ev, E);
    k_pad<<<(N + 255) / 256, 256, 0, stream>>>(cursor, roff, ev, N);
    k_prepw<<<(17 * 16384 + 255) / 256, 256, 0, stream>>>(Ws1, Ws2, whi, wlo);

    int gg = (N + 63) / 64;
    int gs4 = (N + 3) / 4;
    int gs32 = (N + 31) / 32;

    // --- layer 0: z = (A@x)@W0 (pre-BN) + fused stats ---
    k_spmm3<<<(N + 255) / 256, 256, 0, stream>>>(x, ev, roff, dinv, xa, N);
    k_gemm3_stats<ZT><<<gs32, 256, 0, stream>>>(xa, W0, zb, stg(0), N);

    // --- down layers 1..9 ---
    for (int l = 1; l <= 9; l++) {
        const float *gzp, *bzp;
        gb(l - 1, &gzp, &bzp);
        k_gemm_mfma<ZT, SKT><<<gg, 256, 0, stream>>>(
            zb, (const SKT*)nullptr, skip(l - 1), stg(l - 1), gzp, bzp,
            whi + (size_t)(l - 1) * 16384, wlo + (size_t)(l - 1) * 16384, hb, invN, N);
        k_spmm_stats<ZT><<<gs32, 256, 0, stream>>>(hb, ev, roff, dinv, zb, stg(l), N);
    }

    // --- up layers 0..7 ---
    for (int i = 0; i < 8; i++) {
        int zs = 9 + i;
        const float *gzp, *bzp;
        gb(zs, &gzp, &bzp);
        k_gemm_mfma<ZT, SKT><<<gg, 256, 0, stream>>>(
            zb, skip(8 - i), (SKT*)nullptr, stg(zs), gzp, bzp,
            whi + (size_t)(9 + i) * 16384, wlo + (size_t)(9 + i) * 16384, hb, invN, N);
        k_spmm_stats<ZT><<<gs32, 256, 0, stream>>>(hb, ev, roff, dinv, zb, stg(10 + i), N);
    }

    // --- output: sigmoid(A @ ([act17(z) + skip0] @ Wout)) ---
    const float *gzp, *bzp;
    gb(17, &gzp, &bzp);
    k_bnfin<<<1, 128, 0, stream>>>(stg(17), gzp, bzp, aff, invN);
    k_dot<ZT, SKT><<<gs4, 256, 0, stream>>>(zb, skip(0), aff, Wout, tbuf, N);
    k_spmm1<<<(N + 255) / 256, 256, 0, stream>>>(tbuf, ev, roff, dinv, out, N);
}

// ---------------- launch ----------------

extern "C" void kernel_launch(void* const* d_in, const int* in_sizes, int n_in,
                              void* d_out, int out_size, void* d_ws, size_t ws_size,
                              hipStream_t stream) {
    const float* x    = (const float*)d_in[0];
    const int*   ei   = (const int*)d_in[1];
    const float* W0   = (const float*)d_in[2];
    const float* Ws1  = (const float*)d_in[3];
    const float* g1   = (const float*)d_in[4];
    const float* b1   = (const float*)d_in[5];
    const float* Ws2  = (const float*)d_in[6];
    const float* g2   = (const float*)d_in[7];
    const float* b2   = (const float*)d_in[8];
    const float* Wout = (const float*)d_in[9];
    float* out = (float*)d_out;

    int N = in_sizes[0] / 3;
    int E = in_sizes[1] / 2;
    const int* src = ei;
    const int* dst = ei + E;

    size_t nz = (size_t)N * 128;
    size_t Epad = (size_t)E + 15 * (size_t)N + 16;
    auto need = [&](size_t zbytes, size_t skbytes) -> size_t {
        size_t t = 0;
        auto add = [&](size_t b) { t += (b + 255) & ~(size_t)255; };
        add((size_t)(N + 1) * 4);
        add((size_t)N * 4);
        add(Epad * 8);
        add(4096);
        add((size_t)18 * NSTRIPE * 256 * 4);
        add(1024);
        add((size_t)17 * 16384 * 2);
        add((size_t)17 * 16384 * 2);
        add(nz * 2);
        add(nz * zbytes);
        add((size_t)9 * nz * skbytes);
        return t;
    };

    char* ws = (char*)d_ws;
    if (need(4, 2) <= ws_size)          // fp32 z, bf16 skips (~341 MB)
        run_all<float, ushort>(x, src, dst, W0, Ws1, g1, b1, Ws2, g2, b2, Wout, out, ws, N, E, stream);
    else if (need(4, 1) <= ws_size)     // fp32 z, fp8 skips (~225 MB)
        run_all<float, unsigned char>(x, src, dst, W0, Ws1, g1, b1, Ws2, g2, b2, Wout, out, ws, N, E, stream);
    else                                // bf16 z, fp8 skips (~199 MB)
        run_all<ushort, unsigned char>(x, src, dst, W0, Ws1, g1, b1, Ws2, g2, b2, Wout, out, ws, N, E, stream);
}

// Round 16
// 2036.865 us; speedup vs baseline: 1.2983x; 1.0135x over previous
//
#include <hip/hip_runtime.h>
#include <hip/hip_bf16.h>

#define EPSV 1e-5f
#define NSTRIPE 16

typedef unsigned int uint;
typedef unsigned short ushort;
typedef __attribute__((ext_vector_type(8))) __bf16 bf16x8;
typedef __attribute__((ext_vector_type(4))) float f32x4;

static __device__ __forceinline__ float bf2f(ushort u) {
    return __uint_as_float(((uint)u) << 16);
}
static __device__ __forceinline__ ushort f2bf(float f) {
    __hip_bfloat16 h = __float2bfloat16(f);
    return __builtin_bit_cast(ushort, h);
}

// ---------------- fp8 e4m3 codec (low-mem skip tier) ----------------

static __device__ __forceinline__ float e4m3_dec(unsigned char b) {
    int s = b >> 7, E = (b >> 3) & 15, m = b & 7;
    float v = (E == 0) ? (float)m * 0.001953125f
                       : (float)(8 + m) * 0.125f * exp2f((float)(E - 7));
    return s ? -v : v;
}
static __device__ __forceinline__ unsigned char e4m3_enc(float f) {
    unsigned su = (__float_as_uint(f) >> 24) & 0x80u;
    float a = fabsf(f);
    if (!(a < 448.f)) return (unsigned char)(su | 0x7E);
    if (a < 0.015625f) {
        int m = (int)rintf(a * 512.f);
        return (unsigned char)(su | (m >= 8 ? 0x08 : m));
    }
    int e;
    frexpf(a, &e);
    int E = e - 1 + 7;
    float mant = a * exp2f((float)(1 - e)) - 1.0f;
    int mi = (int)rintf(mant * 8.f);
    if (mi >= 8) { mi = 0; E++; }
    if (E >= 16) return (unsigned char)(su | 0x7E);
    if (E == 15 && mi == 7) mi = 6;
    return (unsigned char)(su | (E << 3) | mi);
}

// ---------------- storage traits ----------------

template <typename T> struct IOV;
template <> struct IOV<float> {
    static __device__ __forceinline__ float2 ld2(const float* p) { return *(const float2*)p; }
    static __device__ __forceinline__ void st2(float* p, float a, float b) {
        *(float2*)p = make_float2(a, b);
    }
    static __device__ __forceinline__ void ld8(const float* p, float* v) {
        float4 a = ((const float4*)p)[0], b = ((const float4*)p)[1];
        v[0] = a.x; v[1] = a.y; v[2] = a.z; v[3] = a.w;
        v[4] = b.x; v[5] = b.y; v[6] = b.z; v[7] = b.w;
    }
    static __device__ __forceinline__ void st8(float* p, const float* v) {
        ((float4*)p)[0] = make_float4(v[0], v[1], v[2], v[3]);
        ((float4*)p)[1] = make_float4(v[4], v[5], v[6], v[7]);
    }
};
template <> struct IOV<ushort> {  // bf16 bits
    static __device__ __forceinline__ float2 ld2(const ushort* p) {
        uint u = *(const uint*)p;
        return make_float2(bf2f((ushort)u), bf2f((ushort)(u >> 16)));
    }
    static __device__ __forceinline__ void st2(ushort* p, float a, float b) {
        *(uint*)p = (uint)f2bf(a) | ((uint)f2bf(b) << 16);
    }
    static __device__ __forceinline__ void ld8(const ushort* p, float* v) {
        uint4 u = *(const uint4*)p;
        v[0] = bf2f((ushort)u.x); v[1] = bf2f((ushort)(u.x >> 16));
        v[2] = bf2f((ushort)u.y); v[3] = bf2f((ushort)(u.y >> 16));
        v[4] = bf2f((ushort)u.z); v[5] = bf2f((ushort)(u.z >> 16));
        v[6] = bf2f((ushort)u.w); v[7] = bf2f((ushort)(u.w >> 16));
    }
    static __device__ __forceinline__ void st8(ushort* p, const float* v) {
        uint4 u;
        u.x = (uint)f2bf(v[0]) | ((uint)f2bf(v[1]) << 16);
        u.y = (uint)f2bf(v[2]) | ((uint)f2bf(v[3]) << 16);
        u.z = (uint)f2bf(v[4]) | ((uint)f2bf(v[5]) << 16);
        u.w = (uint)f2bf(v[6]) | ((uint)f2bf(v[7]) << 16);
        *(uint4*)p = u;
    }
};
template <> struct IOV<unsigned char> {  // fp8 e4m3
    static __device__ __forceinline__ float2 ld2(const unsigned char* p) {
        ushort u = *(const ushort*)p;
        return make_float2(e4m3_dec((unsigned char)u), e4m3_dec((unsigned char)(u >> 8)));
    }
    static __device__ __forceinline__ void st2(unsigned char* p, float a, float b) {
        *(ushort*)p = (ushort)e4m3_enc(a) | ((ushort)e4m3_enc(b) << 8);
    }
    static __device__ __forceinline__ void ld8(const unsigned char* p, float* v) {
        uint2 u = *(const uint2*)p;
#pragma unroll
        for (int j = 0; j < 4; j++) v[j] = e4m3_dec((unsigned char)(u.x >> (8 * j)));
#pragma unroll
        for (int j = 0; j < 4; j++) v[4 + j] = e4m3_dec((unsigned char)(u.y >> (8 * j)));
    }
    static __device__ __forceinline__ void st8(unsigned char* p, const float* v) {
        uint2 u = {0, 0};
#pragma unroll
        for (int j = 0; j < 4; j++) u.x |= (uint)e4m3_enc(v[j]) << (8 * j);
#pragma unroll
        for (int j = 0; j < 4; j++) u.y |= (uint)e4m3_enc(v[4 + j]) << (8 * j);
        *(uint2*)p = u;
    }
};

// ---------------- graph setup ----------------

__global__ void k_count(const int* __restrict__ dst, int* __restrict__ cnt, int E) {
    int e = blockIdx.x * blockDim.x + threadIdx.x;
    if (e < E) atomicAdd(&cnt[dst[e]], 1);
}

// sums PADDED counts (rows padded to multiple of 16)
__global__ void k_scan1(const int* __restrict__ cnt, int* __restrict__ bsum, int N) {
    __shared__ int s[256];
    int i = blockIdx.x * 256 + threadIdx.x;
    s[threadIdx.x] = (i < N) ? ((cnt[i] + 15) & ~15) : 0;
    __syncthreads();
    for (int o = 128; o > 0; o >>= 1) {
        if (threadIdx.x < o) s[threadIdx.x] += s[threadIdx.x + o];
        __syncthreads();
    }
    if (threadIdx.x == 0) bsum[blockIdx.x] = s[0];
}

__global__ void k_scan2(int* __restrict__ bsum, int B) {
    __shared__ int s[1024];
    int t = threadIdx.x;
    int orig = (t < B) ? bsum[t] : 0;
    s[t] = orig;
    __syncthreads();
    for (int o = 1; o < 1024; o <<= 1) {
        int v = (t >= o) ? s[t - o] : 0;
        __syncthreads();
        s[t] += v;
        __syncthreads();
    }
    if (t < B) bsum[t] = s[t] - orig;
}

__global__ void k_scan3(const int* __restrict__ cnt, const int* __restrict__ bsum,
                        int* __restrict__ roff, int* __restrict__ cursor,
                        float* __restrict__ dinv, int N) {
    __shared__ int s[256];
    int i = blockIdx.x * 256 + threadIdx.x;
    int v = (i < N) ? cnt[i] : 0;
    int pv = (v + 15) & ~15;
    s[threadIdx.x] = pv;
    __syncthreads();
    for (int o = 1; o < 256; o <<= 1) {
        int u = (threadIdx.x >= o) ? s[threadIdx.x - o] : 0;
        __syncthreads();
        s[threadIdx.x] += u;
        __syncthreads();
    }
    if (i < N) {
        int off = bsum[blockIdx.x] + s[threadIdx.x] - pv;
        roff[i] = off;
        cursor[i] = off;
        dinv[i] = rsqrtf((float)(v + 1));
        if (i == N - 1) roff[N] = off + pv;
    }
}

__global__ void k_scatter(const int* __restrict__ src, const int* __restrict__ dst,
                          const float* __restrict__ dinv, int* __restrict__ cursor,
                          int2* __restrict__ ev, int E) {
    int e = blockIdx.x * blockDim.x + threadIdx.x;
    if (e < E) {
        int s = src[e], d = dst[e];
        int p = atomicAdd(&cursor[d], 1);
        int2 pk;
        pk.x = s;
        pk.y = __float_as_int(dinv[s] * dinv[d]);
        ev[p] = pk;
    }
}

// fill pad slots with zero-weight self edges
__global__ void k_pad(const int* __restrict__ cursor, const int* __restrict__ roff,
                      int2* __restrict__ ev, int N) {
    int i = blockIdx.x * blockDim.x + threadIdx.x;
    if (i >= N) return;
    int p = cursor[i], e = roff[i + 1];
    int2 pk;
    pk.x = i;
    pk.y = 0;
    for (; p < e; p++) ev[p] = pk;
}

// precompute fragment-ordered bf16 hi/lo for all 17 dense weight matrices
__global__ void k_prepw(const float* __restrict__ Ws1, const float* __restrict__ Ws2,
                        ushort* __restrict__ whi, ushort* __restrict__ wlo) {
    int idx = blockIdx.x * blockDim.x + threadIdx.x;
    if (idx >= 17 * 16384) return;
    int L = idx >> 14, r = idx & 16383;
    int f = r >> 9, e = r & 511, lane = e >> 3, j = e & 7;
    int n = (f >> 2) * 16 + (lane & 15);
    int k = (f & 3) * 32 + (lane >> 4) * 8 + j;
    const float* W = (L < 9) ? (Ws1 + (size_t)L * 16384) : (Ws2 + (size_t)(L - 9) * 16384);
    float w = W[(size_t)k * 128 + n];
    ushort hi = f2bf(w);
    whi[idx] = hi;
    wlo[idx] = f2bf(w - bf2f(hi));
}

// ---------------- sparse ops ----------------

__global__ void k_spmm3(const float* __restrict__ X, const int2* __restrict__ ev,
                        const int* __restrict__ roff, const float* __restrict__ dinv,
                        float* __restrict__ XA, int N) {
    int i = blockIdx.x * blockDim.x + threadIdx.x;
    if (i >= N) return;
    float di = dinv[i];
    float w0 = di * di;
    float a0 = X[(size_t)i * 3 + 0] * w0;
    float a1 = X[(size_t)i * 3 + 1] * w0;
    float a2 = X[(size_t)i * 3 + 2] * w0;
    int je = roff[i + 1];
    for (int j = roff[i]; j < je; j++) {
        int2 e = ev[j];
        float w = __int_as_float(e.y);
        a0 += X[(size_t)e.x * 3 + 0] * w;
        a1 += X[(size_t)e.x * 3 + 1] * w;
        a2 += X[(size_t)e.x * 3 + 2] * w;
    }
    XA[(size_t)i * 3 + 0] = a0;
    XA[(size_t)i * 3 + 1] = a1;
    XA[(size_t)i * 3 + 2] = a2;
}

// Z(pre-BN) = A @ H (H bf16) + fused striped stats.
// 16 rows/block (4 per wave, serial): 6250 blocks -> finer dispatch granularity
// (r15's 3125 long blocks capped occupancy at 35%); 8-deep gather batch keeps
// VGPR low; 1.6M stats atomics measured neutral vs 0.8M (r12<->r14).
template <typename ZT>
__global__ __launch_bounds__(256) void k_spmm_stats(
    const ushort* __restrict__ H, const int2* __restrict__ ev,
    const int* __restrict__ roff, const float* __restrict__ dinv,
    ZT* __restrict__ Y, float* __restrict__ st, int N) {
    int lane = threadIdx.x & 63, wv = threadIdx.x >> 6;
    const uint* Hu = (const uint*)H;
    float s0 = 0.f, s1 = 0.f, q0 = 0.f, q1 = 0.f;

#pragma unroll
    for (int r = 0; r < 4; r++) {
        int i = blockIdx.x * 16 + wv * 4 + r;
        if (i >= N) break;
        float di = dinv[i];
        float ws = di * di;
        uint u = Hu[(size_t)i * 64 + lane];
        float a0 = bf2f((ushort)u) * ws, a1 = bf2f((ushort)(u >> 16)) * ws;
        int j = roff[i], je = roff[i + 1];
        for (; j < je; j += 8) {
            int2 e[8];
            uint uu[8];
#pragma unroll
            for (int t = 0; t < 8; t++) e[t] = ev[j + t];
#pragma unroll
            for (int t = 0; t < 8; t++) uu[t] = Hu[(size_t)e[t].x * 64 + lane];
#pragma unroll
            for (int t = 0; t < 8; t++) {
                float w = __int_as_float(e[t].y);
                a0 += bf2f((ushort)uu[t]) * w;
                a1 += bf2f((ushort)(uu[t] >> 16)) * w;
            }
        }
        IOV<ZT>::st2(&Y[(size_t)i * 128 + 2 * lane], a0, a1);
        s0 += a0; q0 += a0 * a0;
        s1 += a1; q1 += a1 * a1;
    }

    __shared__ float ls[4][64][4];
    ls[wv][lane][0] = s0; ls[wv][lane][1] = s1;
    ls[wv][lane][2] = q0; ls[wv][lane][3] = q1;
    __syncthreads();
    if (wv == 0) {
        s0 = ls[0][lane][0] + ls[1][lane][0] + ls[2][lane][0] + ls[3][lane][0];
        s1 = ls[0][lane][1] + ls[1][lane][1] + ls[2][lane][1] + ls[3][lane][1];
        q0 = ls[0][lane][2] + ls[1][lane][2] + ls[2][lane][2] + ls[3][lane][2];
        q1 = ls[0][lane][3] + ls[1][lane][3] + ls[2][lane][3] + ls[3][lane][3];
        float* stp = st + (size_t)(blockIdx.x & (NSTRIPE - 1)) * 256;
        atomicAdd(&stp[2 * lane], s0);
        atomicAdd(&stp[2 * lane + 1], s1);
        atomicAdd(&stp[128 + 2 * lane], q0);
        atomicAdd(&stp[129 + 2 * lane], q1);
    }
}

__global__ void k_spmm1(const float* __restrict__ T, const int2* __restrict__ ev,
                        const int* __restrict__ roff, const float* __restrict__ dinv,
                        float* __restrict__ out, int N) {
    int i = blockIdx.x * blockDim.x + threadIdx.x;
    if (i >= N) return;
    float di = dinv[i];
    float a = T[i] * di * di;
    int je = roff[i + 1];
    for (int j = roff[i]; j < je; j++) {
        int2 e = ev[j];
        a += T[e.x] * __int_as_float(e.y);
    }
    out[i] = 1.0f / (1.0f + expf(-a));
}

// finalize striped stats -> affine (for k_dot only)
__global__ void k_bnfin(const float* __restrict__ st, const float* __restrict__ g,
                        const float* __restrict__ b, float* __restrict__ aff, float invN) {
    int c = threadIdx.x;  // 128
    float S = 0.f, Q = 0.f;
    for (int s = 0; s < NSTRIPE; s++) {
        S += st[(size_t)s * 256 + c];
        Q += st[(size_t)s * 256 + 128 + c];
    }
    float m = S * invN;
    float var = Q * invN - m * m;
    float sc = g[c] * rsqrtf(var + EPSV);
    aff[c] = sc;
    aff[128 + c] = b[c] - m * sc;
}

// ---------------- dense ops ----------------

// z(stage0, pre-BN) = (A@x)@W0 with fused striped stats; 32 rows/block (8/wave)
template <typename ZT>
__global__ __launch_bounds__(256) void k_gemm3_stats(
    const float* __restrict__ XA, const float* __restrict__ W0,
    ZT* __restrict__ Y, float* __restrict__ st, int N) {
    int lane = threadIdx.x & 63, wv = threadIdx.x >> 6;
    int c0 = lane * 2;
    float w00 = W0[c0], w10 = W0[128 + c0], w20 = W0[256 + c0];
    float w01 = W0[c0 + 1], w11 = W0[128 + c0 + 1], w21 = W0[256 + c0 + 1];
    float s0 = 0.f, s1 = 0.f, q0 = 0.f, q1 = 0.f;
#pragma unroll
    for (int r = 0; r < 8; r++) {
        int i = blockIdx.x * 32 + wv * 8 + r;
        if (i >= N) break;
        float x0 = XA[(size_t)i * 3], x1 = XA[(size_t)i * 3 + 1], x2 = XA[(size_t)i * 3 + 2];
        float y0 = x0 * w00 + x1 * w10 + x2 * w20;
        float y1 = x0 * w01 + x1 * w11 + x2 * w21;
        IOV<ZT>::st2(&Y[(size_t)i * 128 + c0], y0, y1);
        s0 += y0; q0 += y0 * y0;
        s1 += y1; q1 += y1 * y1;
    }
    __shared__ float ls[4][64][4];
    ls[wv][lane][0] = s0; ls[wv][lane][1] = s1;
    ls[wv][lane][2] = q0; ls[wv][lane][3] = q1;
    __syncthreads();
    if (wv == 0) {
        s0 = ls[0][lane][0] + ls[1][lane][0] + ls[2][lane][0] + ls[3][lane][0];
        s1 = ls[0][lane][1] + ls[1][lane][1] + ls[2][lane][1] + ls[3][lane][1];
        q0 = ls[0][lane][2] + ls[1][lane][2] + ls[2][lane][2] + ls[3][lane][2];
        q1 = ls[0][lane][3] + ls[1][lane][3] + ls[2][lane][3] + ls[3][lane][3];
        float* stp = st + (size_t)(blockIdx.x & (NSTRIPE - 1)) * 256;
        atomicAdd(&stp[2 * lane], s0);
        atomicAdd(&stp[2 * lane + 1], s1);
        atomicAdd(&stp[128 + 2 * lane], q0);
        atomicAdd(&stp[129 + 2 * lane], q1);
    }
}

// H(bf16) = [ReLU(BN(Z)) + skip_in] @ W  (MFMA; fragment-order W hi/lo staging)
template <typename ZT, typename SKT>
__global__ __launch_bounds__(256) void k_gemm_mfma(
    const ZT* __restrict__ Z, const SKT* __restrict__ skip_in, SKT* __restrict__ skip_out,
    const float* __restrict__ st, const float* __restrict__ gz, const float* __restrict__ bz,
    const ushort* __restrict__ whi, const ushort* __restrict__ wlo,
    ushort* __restrict__ H, float invN, int N) {
    __shared__ ushort sW[16384];  // 32 frags x 512 ushorts
    __shared__ float sA[256];
    int tid = threadIdx.x;
    int wave = tid >> 6, lane = tid & 63;
    int l15 = lane & 15, quad = lane >> 4;

    // phase A: striped-stats partial reduce (16 stripes)
    {
        float acc = 0.f;
#pragma unroll
        for (int s = 0; s < NSTRIPE; s++) acc += st[(size_t)s * 256 + tid];
        sA[tid] = acc;
    }
    // phase B: stage W hi (coalesced, fragment-ordered)
    {
        const uint4* src = (const uint4*)whi;
#pragma unroll
        for (int t = 0; t < 8; t++) ((uint4*)sW)[tid + 256 * t] = src[tid + 256 * t];
    }
    __syncthreads();
    // phase C: finalize BN affine
    if (tid < 128) {
        float S = sA[tid], Q = sA[128 + tid];
        float m = S * invN;
        float var = Q * invN - m * m;
        float sc = gz[tid] * rsqrtf(var + EPSV);
        sA[tid] = sc;
        sA[128 + tid] = bz[tid] - m * sc;
    }
    __syncthreads();

    int row = blockIdx.x * 64 + wave * 16 + l15;
    size_t rowc = (size_t)(row < N ? row : N - 1);

    bf16x8 ahi[4];
#pragma unroll
    for (int kc = 0; kc < 4; kc++) {
        int c0 = kc * 32 + quad * 8;
        float v[8];
        IOV<ZT>::ld8(&Z[rowc * 128 + c0], v);
        float av[8];
#pragma unroll
        for (int jj = 0; jj < 8; jj++) {
            float t = v[jj] * sA[c0 + jj] + sA[128 + c0 + jj];
            av[jj] = fmaxf(t, 0.f);
        }
        if (skip_out && row < N) IOV<SKT>::st8(&skip_out[rowc * 128 + c0], av);
        if (skip_in) {
            float w2[8];
            IOV<SKT>::ld8(&skip_in[rowc * 128 + c0], w2);
#pragma unroll
            for (int jj = 0; jj < 8; jj++) av[jj] += w2[jj];
        }
        bf16x8 fh;
#pragma unroll
        for (int jj = 0; jj < 8; jj++) fh[jj] = (__bf16)av[jj];
        ahi[kc] = fh;
    }

    f32x4 acc[8];
#pragma unroll
    for (int ct = 0; ct < 8; ct++) {
        f32x4 z0 = {0.f, 0.f, 0.f, 0.f};
        acc[ct] = z0;
    }

    // pass 1: Ahi * Whi
#pragma unroll
    for (int ct = 0; ct < 8; ct++) {
#pragma unroll
        for (int kc = 0; kc < 4; kc++) {
            bf16x8 b = *(const bf16x8*)&sW[(ct * 4 + kc) * 512 + lane * 8];
            acc[ct] = __builtin_amdgcn_mfma_f32_16x16x32_bf16(ahi[kc], b, acc[ct], 0, 0, 0);
        }
    }
    __syncthreads();
    // stage W lo (coalesced)
    {
        const uint4* src = (const uint4*)wlo;
#pragma unroll
        for (int t = 0; t < 8; t++) ((uint4*)sW)[tid + 256 * t] = src[tid + 256 * t];
    }
    __syncthreads();
    // pass 2: Ahi * Wlo
#pragma unroll
    for (int ct = 0; ct < 8; ct++) {
#pragma unroll
        for (int kc = 0; kc < 4; kc++) {
            bf16x8 b = *(const bf16x8*)&sW[(ct * 4 + kc) * 512 + lane * 8];
            acc[ct] = __builtin_amdgcn_mfma_f32_16x16x32_bf16(ahi[kc], b, acc[ct], 0, 0, 0);
        }
    }
    __syncthreads();
    // epilogue: C layout col=l15, row=quad*4+reg -> LDS -> coalesced bf16 store
    ushort* sC = sW;
#pragma unroll
    for (int ct = 0; ct < 8; ct++)
#pragma unroll
        for (int reg = 0; reg < 4; reg++) {
            int r = wave * 16 + quad * 4 + reg;
            sC[r * 136 + ct * 16 + l15] = f2bf(acc[ct][reg]);
        }
    __syncthreads();
    for (int t = tid; t < 1024; t += 256) {
        int r = t >> 4, c4 = t & 15;
        int grow = blockIdx.x * 64 + r;
        if (grow < N)
            ((uint4*)(H + (size_t)grow * 128))[c4] = *(const uint4*)&sC[r * 136 + c4 * 8];
    }
}

// t = [ReLU(BN(Z)) + skip0(post-act)] @ Wout  (wave per row; affine precomputed)
template <typename ZT, typename SKT>
__global__ __launch_bounds__(256) void k_dot(
    const ZT* __restrict__ Z, const SKT* __restrict__ S0,
    const float* __restrict__ aff, const float* __restrict__ Wout,
    float* __restrict__ T, int N) {
    int i = blockIdx.x * 4 + (threadIdx.x >> 6);
    if (i >= N) return;
    int lane = threadIdx.x & 63;
    int c0 = 2 * lane, c1 = c0 + 1;
    float2 z = IOV<ZT>::ld2(&Z[(size_t)i * 128 + c0]);
    float2 s = IOV<SKT>::ld2(&S0[(size_t)i * 128 + c0]);
    float p0 = fmaxf(z.x * aff[c0] + aff[128 + c0], 0.f) + s.x;
    float p1 = fmaxf(z.y * aff[c1] + aff[128 + c1], 0.f) + s.y;
    float a = p0 * Wout[c0] + p1 * Wout[c1];
    for (int o = 32; o > 0; o >>= 1) a += __shfl_down(a, o);
    if (lane == 0) T[i] = a;
}

// ---------------- templated pipeline ----------------

template <typename ZT, typename SKT>
static void run_all(const float* x, const int* src, const int* dst, const float* W0,
                    const float* Ws1, const float* g1, const float* b1,
                    const float* Ws2, const float* g2, const float* b2,
                    const float* Wout, float* out, char* ws, int N, int E,
                    hipStream_t stream) {
    char* p = ws;
    auto alloc = [&](size_t bytes) -> void* {
        void* r = (void*)p;
        p += (bytes + 255) & ~(size_t)255;
        return r;
    };
    size_t Epad = (size_t)E + 15 * (size_t)N + 16;
    int*   roff   = (int*)alloc((size_t)(N + 1) * 4);
    float* dinv   = (float*)alloc((size_t)N * 4);
    int2*  ev     = (int2*)alloc(Epad * 8);
    int*   bsum   = (int*)alloc(4096);
    float* st_all = (float*)alloc((size_t)18 * NSTRIPE * 256 * 4);
    float* aff    = (float*)alloc(1024);
    ushort* whi   = (ushort*)alloc((size_t)17 * 16384 * 2);
    ushort* wlo   = (ushort*)alloc((size_t)17 * 16384 * 2);
    size_t nz = (size_t)N * 128;
    ushort* hb = (ushort*)alloc(nz * 2);
    ZT* zb = (ZT*)alloc(nz * sizeof(ZT));
    SKT* skips = (SKT*)alloc((size_t)9 * nz * sizeof(SKT));
    auto skip = [&](int s) { return skips + (size_t)s * nz; };
    auto stg  = [&](int s) { return st_all + (size_t)s * NSTRIPE * 256; };

    // lifetime-disjoint aliases
    int* cnt    = (int*)skip(8);
    int* cursor = (int*)((char*)skip(8) + (((size_t)N * 4 + 255) & ~(size_t)255));
    float* xa   = (float*)hb;
    float* tbuf = (float*)hb;

    float invN = 1.0f / (float)N;
    auto gb = [&](int stage, const float** g, const float** b) {
        if (stage <= 9) { *g = g1 + (size_t)stage * 128; *b = b1 + (size_t)stage * 128; }
        else { *g = g2 + (size_t)(stage - 10) * 128; *b = b2 + (size_t)(stage - 10) * 128; }
    };

    // --- setup: CSR (padded to %16) + weight prep ---
    hipMemsetAsync(st_all, 0, (size_t)18 * NSTRIPE * 256 * 4, stream);
    hipMemsetAsync(cnt, 0, (size_t)N * 4, stream);
    k_count<<<(E + 255) / 256, 256, 0, stream>>>(dst, cnt, E);
    int B = (N + 255) / 256;
    k_scan1<<<B, 256, 0, stream>>>(cnt, bsum, N);
    k_scan2<<<1, 1024, 0, stream>>>(bsum, B);
    k_scan3<<<B, 256, 0, stream>>>(cnt, bsum, roff, cursor, dinv, N);
    k_scatter<<<(E + 255) / 256, 256, 0, stream>>>(src, dst, dinv, cursor, ev, E);
    k_pad<<<(N + 255) / 256, 256, 0, stream>>>(cursor, roff, ev, N);
    k_prepw<<<(17 * 16384 + 255) / 256, 256, 0, stream>>>(Ws1, Ws2, whi, wlo);

    int gg = (N + 63) / 64;
    int gs4 = (N + 3) / 4;
    int gs16 = (N + 15) / 16;
    int gs32 = (N + 31) / 32;

    // --- layer 0: z = (A@x)@W0 (pre-BN) + fused stats ---
    k_spmm3<<<(N + 255) / 256, 256, 0, stream>>>(x, ev, roff, dinv, xa, N);
    k_gemm3_stats<ZT><<<gs32, 256, 0, stream>>>(xa, W0, zb, stg(0), N);

    // --- down layers 1..9 ---
    for (int l = 1; l <= 9; l++) {
        const float *gzp, *bzp;
        gb(l - 1, &gzp, &bzp);
        k_gemm_mfma<ZT, SKT><<<gg, 256, 0, stream>>>(
            zb, (const SKT*)nullptr, skip(l - 1), stg(l - 1), gzp, bzp,
            whi + (size_t)(l - 1) * 16384, wlo + (size_t)(l - 1) * 16384, hb, invN, N);
        k_spmm_stats<ZT><<<gs16, 256, 0, stream>>>(hb, ev, roff, dinv, zb, stg(l), N);
    }

    // --- up layers 0..7 ---
    for (int i = 0; i < 8; i++) {
        int zs = 9 + i;
        const float *gzp, *bzp;
        gb(zs, &gzp, &bzp);
        k_gemm_mfma<ZT, SKT><<<gg, 256, 0, stream>>>(
            zb, skip(8 - i), (SKT*)nullptr, stg(zs), gzp, bzp,
            whi + (size_t)(9 + i) * 16384, wlo + (size_t)(9 + i) * 16384, hb, invN, N);
        k_spmm_stats<ZT><<<gs16, 256, 0, stream>>>(hb, ev, roff, dinv, zb, stg(10 + i), N);
    }

    // --- output: sigmoid(A @ ([act17(z) + skip0] @ Wout)) ---
    const float *gzp, *bzp;
    gb(17, &gzp, &bzp);
    k_bnfin<<<1, 128, 0, stream>>>(stg(17), gzp, bzp, aff, invN);
    k_dot<ZT, SKT><<<gs4, 256, 0, stream>>>(zb, skip(0), aff, Wout, tbuf, N);
    k_spmm1<<<(N + 255) / 256, 256, 0, stream>>>(tbuf, ev, roff, dinv, out, N);
}

// ---------------- launch ----------------

extern "C" void kernel_launch(void* const* d_in, const int* in_sizes, int n_in,
                              void* d_out, int out_size, void* d_ws, size_t ws_size,
                              hipStream_t stream) {
    const float* x    = (const float*)d_in[0];
    const int*   ei   = (const int*)d_in[1];
    const float* W0   = (const float*)d_in[2];
    const float* Ws1  = (const float*)d_in[3];
    const float* g1   = (const float*)d_in[4];
    const float* b1   = (const float*)d_in[5];
    const float* Ws2  = (const float*)d_in[6];
    const float* g2   = (const float*)d_in[7];
    const float* b2   = (const float*)d_in[8];
    const float* Wout = (const float*)d_in[9];
    float* out = (float*)d_out;

    int N = in_sizes[0] / 3;
    int E = in_sizes[1] / 2;
    const int* src = ei;
    const int* dst = ei + E;

    size_t nz = (size_t)N * 128;
    size_t Epad = (size_t)E + 15 * (size_t)N + 16;
    auto need = [&](size_t zbytes, size_t skbytes) -> size_t {
        size_t t = 0;
        auto add = [&](size_t b) { t += (b + 255) & ~(size_t)255; };
        add((size_t)(N + 1) * 4);
        add((size_t)N * 4);
        add(Epad * 8);
        add(4096);
        add((size_t)18 * NSTRIPE * 256 * 4);
        add(1024);
        add((size_t)17 * 16384 * 2);
        add((size_t)17 * 16384 * 2);
        add(nz * 2);
        add(nz * zbytes);
        add((size_t)9 * nz * skbytes);
        return t;
    };

    char* ws = (char*)d_ws;
    if (need(4, 2) <= ws_size)          // fp32 z, bf16 skips (~341 MB)
        run_all<float, ushort>(x, src, dst, W0, Ws1, g1, b1, Ws2, g2, b2, Wout, out, ws, N, E, stream);
    else if (need(4, 1) <= ws_size)     // fp32 z, fp8 skips (~225 MB)
        run_all<float, unsigned char>(x, src, dst, W0, Ws1, g1, b1, Ws2, g2, b2, Wout, out, ws, N, E, stream);
    else                                // bf16 z, fp8 skips (~199 MB)
        run_all<ushort, unsigned char>(x, src, dst, W0, Ws1, g1, b1, Ws2, g2, b2, Wout, out, ws, N, E, stream);
}